// Round 1
// baseline (552.349 us; speedup 1.0000x reference)
//
#include <hip/hip_runtime.h>
#include <hip/hip_bf16.h>
#include <stdint.h>
#include <math.h>

#define BB 32768
#define FEAT 512
#define SPD_H 128
#define CTRL_H 256
#define NCMD 4

typedef __attribute__((ext_vector_type(8))) short bf16x8;
typedef __attribute__((ext_vector_type(4))) float f32x4;

__device__ __forceinline__ unsigned short f2bf(float f) {
  union { float f; uint32_t u; } v; v.f = f;
  uint32_t u = v.u;
  return (unsigned short)((u + 0x7fffu + ((u >> 16) & 1u)) >> 16); // RNE
}
__device__ __forceinline__ float bf2f(unsigned short h) {
  union { uint32_t u; float f; } v; v.u = ((uint32_t)h) << 16; return v.f;
}

// ---------------- feat f32 -> bf16 into A_join[:, 0:512] (stride 640) ----------
__global__ void k_convert_feat(const float* __restrict__ feat,
                               unsigned short* __restrict__ ajoin) {
  int idx = blockIdx.x * 256 + threadIdx.x;       // over BB*128
  int i = idx >> 7;
  int j4 = (idx & 127) << 2;
  float4 f = *(const float4*)(feat + (size_t)i * FEAT + j4);
  ushort4 o;
  o.x = f2bf(f.x); o.y = f2bf(f.y); o.z = f2bf(f.z); o.w = f2bf(f.w);
  *(ushort4*)(ajoin + (size_t)i * 640 + j4) = o;
}

// ---------------- weight transpose+convert: W[K,N] f32 -> Wt[N,K] bf16 --------
struct WSeg { const float* src; unsigned short* dst; int K; int N; };
struct WSegs { WSeg s[13]; };
__global__ void k_wt(WSegs segs) {
  WSeg sg = segs.s[blockIdx.y];
  int idx = blockIdx.x * 256 + threadIdx.x;
  int total = sg.K * sg.N;
  if (idx >= total) return;
  int n = idx / sg.K;
  int k = idx - n * sg.K;
  sg.dst[idx] = f2bf(sg.src[(size_t)k * sg.N + n]);
}

// ---------------- ms layer1: h1[i][j] = relu(speed[i]*w1[j] + b1[j]) ----------
__global__ void k_ms1(const float* __restrict__ speed, const float* __restrict__ w1,
                      const float* __restrict__ b1, unsigned short* __restrict__ h1) {
  int idx = blockIdx.x * 256 + threadIdx.x;       // over BB*32
  int i = idx >> 5;
  int j4 = (idx & 31) << 2;
  float s = speed[i];
  float4 w = *(const float4*)(w1 + j4);
  float4 b = *(const float4*)(b1 + j4);
  ushort4 o;
  o.x = f2bf(fmaxf(fmaf(s, w.x, b.x), 0.f));
  o.y = f2bf(fmaxf(fmaf(s, w.y, b.y), 0.f));
  o.z = f2bf(fmaxf(fmaf(s, w.z, b.z), 0.f));
  o.w = f2bf(fmaxf(fmaf(s, w.w, b.w), 0.f));
  *(ushort4*)(h1 + (size_t)i * SPD_H + j4) = o;
}

// ---------------- generic bf16 MFMA GEMM: C = act(A @ Wt^T + bias) ------------
// A: [M,K] bf16 row-major (lda), optional row gather via perm.
// Wt: [N,K] bf16 row-major (i.e. W transposed), per-expert stride wstride.
// seg: [NCMD+1] device row offsets (grouped mode) or nullptr (dense, e=0).
// Tile 128x128, BK=32, 4 waves (2x2), mfma_f32_16x16x32_bf16.
template<bool RELU>
__launch_bounds__(256)
__global__ void k_gemm(const unsigned short* __restrict__ A, int lda,
                       const int* __restrict__ perm,
                       const int* __restrict__ seg,
                       const unsigned short* __restrict__ Wt, int wstride,
                       const float* __restrict__ bias, int bstride,
                       unsigned short* __restrict__ C, int ldc,
                       int M, int N, int K) {
  __shared__ unsigned short As[128 * 40];   // padded: 40 elems = 80B row stride
  __shared__ unsigned short Bs[128 * 40];

  const int e = blockIdx.z;
  int m_start = 0, m_cnt = M;
  if (seg) { m_start = seg[e]; m_cnt = seg[e + 1] - m_start; }
  const int m0 = blockIdx.y * 128;
  if (m0 >= m_cnt) return;
  const int n0 = blockIdx.x * 128;
  const unsigned short* W = Wt + (size_t)e * wstride;
  const float* bi = bias + (size_t)e * bstride;

  const int t = threadIdx.x;
  const int w = t >> 6, lane = t & 63;
  const int wm = w & 1, wn = w >> 1;

  f32x4 acc[4][4];
#pragma unroll
  for (int i = 0; i < 4; ++i)
#pragma unroll
    for (int j = 0; j < 4; ++j)
#pragma unroll
      for (int r = 0; r < 4; ++r) acc[i][j][r] = 0.f;

  const int fr = lane & 15;
  const int fk = (lane >> 4) * 8;

  for (int k0 = 0; k0 < K; k0 += 32) {
    // stage A (128x32) and B (128x32) -- 16B per thread-segment, 2 iters each
#pragma unroll
    for (int it = 0; it < 2; ++it) {
      int s = t + it * 256;                 // 0..511
      int row = s >> 2, sg = s & 3;
      int rl = m0 + row;
      if (rl >= m_cnt) rl = m_cnt - 1;
      int grow = perm ? perm[m_start + rl] : (m_start + rl);
      uint4 va = *(const uint4*)(A + (size_t)grow * lda + k0 + sg * 8);
      *(uint4*)(As + row * 40 + sg * 8) = va;
      uint4 vb = *(const uint4*)(W + (size_t)(n0 + row) * K + k0 + sg * 8);
      *(uint4*)(Bs + row * 40 + sg * 8) = vb;
    }
    __syncthreads();

    bf16x8 af[4], bfv[4];
#pragma unroll
    for (int i = 0; i < 4; ++i)
      af[i] = *(const bf16x8*)(As + (wm * 64 + i * 16 + fr) * 40 + fk);
#pragma unroll
    for (int j = 0; j < 4; ++j)
      bfv[j] = *(const bf16x8*)(Bs + (wn * 64 + j * 16 + fr) * 40 + fk);
#pragma unroll
    for (int i = 0; i < 4; ++i)
#pragma unroll
      for (int j = 0; j < 4; ++j)
        acc[i][j] = __builtin_amdgcn_mfma_f32_16x16x32_bf16(af[i], bfv[j], acc[i][j], 0, 0, 0);
    __syncthreads();
  }

  // epilogue: C/D layout col=lane&15, row=(lane>>4)*4+reg  [m89/m91-verified]
  const int rquad = (lane >> 4) * 4;
  const int cidx = lane & 15;
#pragma unroll
  for (int j = 0; j < 4; ++j) {
    int col = n0 + wn * 64 + j * 16 + cidx;
    float bv = bi[col];
#pragma unroll
    for (int i = 0; i < 4; ++i) {
      int rl = m0 + wm * 64 + i * 16 + rquad;
#pragma unroll
      for (int r = 0; r < 4; ++r) {
        if (rl + r < m_cnt) {
          float v = acc[i][j][r] + bv;
          if (RELU) v = fmaxf(v, 0.f);
          C[(size_t)(m_start + rl + r) * ldc + col] = f2bf(v);
        }
      }
    }
  }
}

// ---------------- command bucketing ------------------------------------------
__global__ void k_hist(const int* __restrict__ cmd, int* __restrict__ counts) {
  __shared__ int lc[NCMD];
  int t = threadIdx.x;
  if (t < NCMD) lc[t] = 0;
  __syncthreads();
  int i = blockIdx.x * 256 + t;
  atomicAdd(&lc[cmd[i]], 1);
  __syncthreads();
  if (t < NCMD) atomicAdd(&counts[t], lc[t]);
}
__global__ void k_offs(int* __restrict__ cnt) {
  // cnt layout: counts[4], offs[5], cursor[4]
  int* offs = cnt + 4;
  int* cur = cnt + 9;
  offs[0] = 0;
  for (int e = 0; e < NCMD; ++e) { offs[e + 1] = offs[e] + cnt[e]; cur[e] = offs[e]; }
}
__global__ void k_scatter(const int* __restrict__ cmd, int* __restrict__ cur,
                          int* __restrict__ perm) {
  int i = blockIdx.x * 256 + threadIdx.x;
  int c = cmd[i];
  int p = atomicAdd(&cur[c], 1);
  perm[p] = i;
}

// ---------------- v_p = h2 @ sp_w3 + b  (K=256, one wave per row) -------------
__global__ void k_vp(const unsigned short* __restrict__ h, const float* __restrict__ w,
                     const float* __restrict__ b, float* __restrict__ out) {
  int t = threadIdx.x;
  int row = blockIdx.x * 4 + (t >> 6);
  int lane = t & 63;
  int k = lane * 4;
  ushort4 hv = *(const ushort4*)(h + (size_t)row * CTRL_H + k);
  float4 wv = *(const float4*)(w + k);
  float a = bf2f(hv.x) * wv.x + bf2f(hv.y) * wv.y + bf2f(hv.z) * wv.z + bf2f(hv.w) * wv.w;
#pragma unroll
  for (int m = 32; m; m >>= 1) a += __shfl_xor(a, m, 64);
  if (lane == 0) out[row] = a + b[0];
}

// ------- actions: a = h2 @ ctrl_w3[e] + b3[e]; activations; scatter back ------
__global__ void k_act(const unsigned short* __restrict__ h, const int* __restrict__ perm,
                      const int* __restrict__ offs, const float* __restrict__ w3,
                      const float* __restrict__ b3, float* __restrict__ out) {
  int t = threadIdx.x;
  int p = blockIdx.x * 4 + (t >> 6);
  int lane = t & 63;
  int e = (p >= offs[1]) + (p >= offs[2]) + (p >= offs[3]);
  int orig = perm[p];
  int k = lane * 4;
  ushort4 hv = *(const ushort4*)(h + (size_t)p * CTRL_H + k);
  float hh[4] = { bf2f(hv.x), bf2f(hv.y), bf2f(hv.z), bf2f(hv.w) };
  const float* wp = w3 + ((size_t)e * CTRL_H + k) * 3;
  float a0 = 0.f, a1 = 0.f, a2 = 0.f;
#pragma unroll
  for (int q = 0; q < 4; ++q) {
    a0 = fmaf(hh[q], wp[q * 3 + 0], a0);
    a1 = fmaf(hh[q], wp[q * 3 + 1], a1);
    a2 = fmaf(hh[q], wp[q * 3 + 2], a2);
  }
#pragma unroll
  for (int m = 32; m; m >>= 1) {
    a0 += __shfl_xor(a0, m, 64);
    a1 += __shfl_xor(a1, m, 64);
    a2 += __shfl_xor(a2, m, 64);
  }
  if (lane == 0) {
    a0 += b3[e * 3 + 0]; a1 += b3[e * 3 + 1]; a2 += b3[e * 3 + 2];
    out[BB + orig]     = 1.f / (1.f + __expf(-a0));   // throttle = sigmoid(a0)
    out[2 * BB + orig] = 1.f / (1.f + __expf(-a2));   // brake    = sigmoid(a2)
    out[3 * BB + orig] = tanhf(a1);                   // steering = tanh(a1)
  }
}

static inline size_t align256(size_t x) { return (x + 255) & ~(size_t)255; }

extern "C" void kernel_launch(void* const* d_in, const int* in_sizes, int n_in,
                              void* d_out, int out_size, void* d_ws, size_t ws_size,
                              hipStream_t stream) {
  const float* feat   = (const float*)d_in[0];
  const float* speed  = (const float*)d_in[1];
  const int*   command= (const int*)d_in[2];
  const float* ms_w1  = (const float*)d_in[3];
  const float* ms_b1  = (const float*)d_in[4];
  const float* ms_w2  = (const float*)d_in[5];
  const float* ms_b2  = (const float*)d_in[6];
  const float* ms_w3  = (const float*)d_in[7];
  const float* ms_b3  = (const float*)d_in[8];
  const float* sp_w1  = (const float*)d_in[9];
  const float* sp_b1  = (const float*)d_in[10];
  const float* sp_w2  = (const float*)d_in[11];
  const float* sp_b2  = (const float*)d_in[12];
  const float* sp_w3  = (const float*)d_in[13];
  const float* sp_b3  = (const float*)d_in[14];
  const float* join_w = (const float*)d_in[15];
  const float* join_b = (const float*)d_in[16];
  const float* ctrl_w1= (const float*)d_in[17];
  const float* ctrl_b1= (const float*)d_in[18];
  const float* ctrl_w2= (const float*)d_in[19];
  const float* ctrl_b2= (const float*)d_in[20];
  const float* ctrl_w3= (const float*)d_in[21];
  const float* ctrl_b3= (const float*)d_in[22];
  float* out = (float*)d_out;

  char* ws = (char*)d_ws;
  size_t off = 0;
  auto alloc = [&](size_t bytes) -> char* { char* p = ws + off; off = align256(off + bytes); return p; };

  unsigned short* ajoin  = (unsigned short*)alloc((size_t)BB * 640 * 2);  // [B,640] bf16
  unsigned short* joined = (unsigned short*)alloc((size_t)BB * 512 * 2);  // [B,512] bf16
  unsigned short* msh1   = joined;                                        // alias (dead before joined写)
  unsigned short* msh2   = joined + (size_t)BB * SPD_H;
  unsigned short* sph1   = (unsigned short*)alloc((size_t)BB * 256 * 2);  // reused as ch1
  unsigned short* sph2   = (unsigned short*)alloc((size_t)BB * 256 * 2);  // reused as ch2
  unsigned short* wtp    = (unsigned short*)alloc(1343488ull * 2);
  int* perm = (int*)alloc((size_t)BB * 4);
  int* cnt  = (int*)alloc(64);   // counts[4], offs[5], cursor[4]

  unsigned short* ms_w2t  = wtp;             // [128][128]
  unsigned short* ms_w3t  = wtp + 16384;     // [128][128]
  unsigned short* sp_w1t  = wtp + 32768;     // [256][512]
  unsigned short* sp_w2t  = wtp + 163840;    // [256][256]
  unsigned short* join_wt = wtp + 229376;    // [512][640]
  unsigned short* c_w1t   = wtp + 557056;    // [4][256][512]
  unsigned short* c_w2t   = wtp + 1081344;   // [4][256][256]

  WSegs S;
  S.s[0] = { ms_w2, ms_w2t, 128, 128 };
  S.s[1] = { ms_w3, ms_w3t, 128, 128 };
  S.s[2] = { sp_w1, sp_w1t, 512, 256 };
  S.s[3] = { sp_w2, sp_w2t, 256, 256 };
  S.s[4] = { join_w, join_wt, 640, 512 };
  for (int e = 0; e < 4; ++e) S.s[5 + e] = { ctrl_w1 + (size_t)e * 512 * 256, c_w1t + (size_t)e * 131072, 512, 256 };
  for (int e = 0; e < 4; ++e) S.s[9 + e] = { ctrl_w2 + (size_t)e * 256 * 256, c_w2t + (size_t)e * 65536, 256, 256 };

  hipMemsetAsync(cnt, 0, 16, stream);
  k_wt<<<dim3(1280, 13, 1), 256, 0, stream>>>(S);
  k_convert_feat<<<(BB * 128) / 256, 256, 0, stream>>>(feat, ajoin);
  k_ms1<<<(BB * 32) / 256, 256, 0, stream>>>(speed, ms_w1, ms_b1, msh1);

  // ms: h2 = relu(h1 @ w2 + b2); v = h2 @ w3 + b3 -> A_join[:,512:640]
  k_gemm<true ><<<dim3(1, 256, 1), 256, 0, stream>>>(msh1, 128, nullptr, nullptr,
      ms_w2t, 0, ms_b2, 0, msh2, 128, BB, 128, 128);
  k_gemm<false><<<dim3(1, 256, 1), 256, 0, stream>>>(msh2, 128, nullptr, nullptr,
      ms_w3t, 0, ms_b3, 0, ajoin + 512, 640, BB, 128, 128);

  // speed-pred: sph1 = relu(feat @ sp_w1 + b), sph2 = relu(sph1 @ sp_w2 + b), v_p
  k_gemm<true ><<<dim3(2, 256, 1), 256, 0, stream>>>(ajoin, 640, nullptr, nullptr,
      sp_w1t, 0, sp_b1, 0, sph1, 256, BB, 256, 512);
  k_gemm<true ><<<dim3(2, 256, 1), 256, 0, stream>>>(sph1, 256, nullptr, nullptr,
      sp_w2t, 0, sp_b2, 0, sph2, 256, BB, 256, 256);
  k_vp<<<BB / 4, 256, 0, stream>>>(sph2, sp_w3, sp_b3, out);

  // join: joined = A_join @ join_w + join_b
  k_gemm<false><<<dim3(4, 256, 1), 256, 0, stream>>>(ajoin, 640, nullptr, nullptr,
      join_wt, 0, join_b, 0, joined, 512, BB, 512, 640);

  // bucket by command
  k_hist<<<BB / 256, 256, 0, stream>>>(command, cnt);
  k_offs<<<1, 1, 0, stream>>>(cnt);
  k_scatter<<<BB / 256, 256, 0, stream>>>(command, cnt + 9, perm);

  // control heads (grouped, only selected expert per sample)
  k_gemm<true ><<<dim3(2, 256, 4), 256, 0, stream>>>(joined, 512, perm, cnt + 4,
      c_w1t, 131072, ctrl_b1, 256, sph1 /*ch1*/, 256, BB, 256, 512);
  k_gemm<true ><<<dim3(2, 256, 4), 256, 0, stream>>>(sph1, 256, nullptr, cnt + 4,
      c_w2t, 65536, ctrl_b2, 256, sph2 /*ch2*/, 256, BB, 256, 256);
  k_act<<<BB / 4, 256, 0, stream>>>(sph2, perm, cnt + 4, ctrl_w3, ctrl_b3, out);
}

// Round 2
// 359.737 us; speedup vs baseline: 1.5354x; 1.5354x over previous
//
#include <hip/hip_runtime.h>
#include <hip/hip_bf16.h>
#include <stdint.h>
#include <math.h>

#define BB 32768
#define FEAT 512
#define SPD_H 128
#define CTRL_H 256
#define NCMD 4

typedef __attribute__((ext_vector_type(8))) short bf16x8;
typedef __attribute__((ext_vector_type(4))) float f32x4;

__device__ __forceinline__ unsigned short f2bf(float f) {
  union { float f; uint32_t u; } v; v.f = f;
  uint32_t u = v.u;
  return (unsigned short)((u + 0x7fffu + ((u >> 16) & 1u)) >> 16); // RNE
}
__device__ __forceinline__ float bf2f(unsigned short h) {
  union { uint32_t u; float f; } v; v.u = ((uint32_t)h) << 16; return v.f;
}

// ---------------- feat f32 -> bf16 into A_join[:, 0:512] (stride 640) ----------
__global__ void k_convert_feat(const float* __restrict__ feat,
                               unsigned short* __restrict__ ajoin) {
  int idx = blockIdx.x * 256 + threadIdx.x;       // over BB*128
  int i = idx >> 7;
  int j4 = (idx & 127) << 2;
  float4 f = *(const float4*)(feat + (size_t)i * FEAT + j4);
  ushort4 o;
  o.x = f2bf(f.x); o.y = f2bf(f.y); o.z = f2bf(f.z); o.w = f2bf(f.w);
  *(ushort4*)(ajoin + (size_t)i * 640 + j4) = o;
}

// ------- weight transpose+convert: W[K,N] f32 -> Wt[N,K] bf16, 32x32 LDS tiles -
struct WSeg { const float* src; unsigned short* dst; int K; int N; };
struct WSegs { WSeg s[13]; };
__global__ void k_wt(WSegs segs) {
  WSeg sg = segs.s[blockIdx.y];
  int tkx = sg.K >> 5, tnx = sg.N >> 5;
  int tile = blockIdx.x;
  if (tile >= tkx * tnx) return;
  int tn = tile / tkx;
  int tk = tile - tn * tkx;
  int k0 = tk * 32, n0 = tn * 32;
  __shared__ float tb[32][33];
  int tx = threadIdx.x & 31, ty = threadIdx.x >> 5;   // ty 0..7
#pragma unroll
  for (int j = 0; j < 4; ++j)
    tb[ty + j * 8][tx] = sg.src[(size_t)(k0 + ty + j * 8) * sg.N + n0 + tx];
  __syncthreads();
#pragma unroll
  for (int j = 0; j < 4; ++j)
    sg.dst[(size_t)(n0 + ty + j * 8) * sg.K + k0 + tx] = f2bf(tb[tx][ty + j * 8]);
}

// ---------------- ms layer1: h1[i][j] = relu(speed[i]*w1[j] + b1[j]) ----------
__global__ void k_ms1(const float* __restrict__ speed, const float* __restrict__ w1,
                      const float* __restrict__ b1, unsigned short* __restrict__ h1) {
  int idx = blockIdx.x * 256 + threadIdx.x;       // over BB*32
  int i = idx >> 5;
  int j4 = (idx & 31) << 2;
  float s = speed[i];
  float4 w = *(const float4*)(w1 + j4);
  float4 b = *(const float4*)(b1 + j4);
  ushort4 o;
  o.x = f2bf(fmaxf(fmaf(s, w.x, b.x), 0.f));
  o.y = f2bf(fmaxf(fmaf(s, w.y, b.y), 0.f));
  o.z = f2bf(fmaxf(fmaf(s, w.z, b.z), 0.f));
  o.w = f2bf(fmaxf(fmaf(s, w.w, b.w), 0.f));
  *(ushort4*)(h1 + (size_t)i * SPD_H + j4) = o;
}

// ---------------- generic bf16 MFMA GEMM: C = act(A @ Wt^T + bias) ------------
template<bool RELU>
__launch_bounds__(256)
__global__ void k_gemm(const unsigned short* __restrict__ A, int lda,
                       const int* __restrict__ perm,
                       const int* __restrict__ seg,
                       const unsigned short* __restrict__ Wt, int wstride,
                       const float* __restrict__ bias, int bstride,
                       unsigned short* __restrict__ C, int ldc,
                       int M, int N, int K) {
  __shared__ unsigned short As[128 * 40];   // padded: 40 elems = 80B row stride
  __shared__ unsigned short Bs[128 * 40];

  const int e = blockIdx.z;
  int m_start = 0, m_cnt = M;
  if (seg) { m_start = seg[e]; m_cnt = seg[e + 1] - m_start; }
  const int m0 = blockIdx.y * 128;
  if (m0 >= m_cnt) return;
  const int n0 = blockIdx.x * 128;
  const unsigned short* W = Wt + (size_t)e * wstride;
  const float* bi = bias + (size_t)e * bstride;

  const int t = threadIdx.x;
  const int w = t >> 6, lane = t & 63;
  const int wm = w & 1, wn = w >> 1;

  f32x4 acc[4][4];
#pragma unroll
  for (int i = 0; i < 4; ++i)
#pragma unroll
    for (int j = 0; j < 4; ++j)
#pragma unroll
      for (int r = 0; r < 4; ++r) acc[i][j][r] = 0.f;

  const int fr = lane & 15;
  const int fk = (lane >> 4) * 8;

  // hoist k-invariant staging addresses (perm lookup was a per-k global load)
  const unsigned short* ap[2]; const unsigned short* bp[2]; int lo[2];
#pragma unroll
  for (int it = 0; it < 2; ++it) {
    int s = t + it * 256;                 // 0..511
    int row = s >> 2, sg8 = (s & 3) * 8;
    int rl = m0 + row;
    if (rl >= m_cnt) rl = m_cnt - 1;
    int grow = perm ? perm[m_start + rl] : (m_start + rl);
    ap[it] = A + (size_t)grow * lda + sg8;
    bp[it] = W + (size_t)(n0 + row) * K + sg8;
    lo[it] = row * 40 + sg8;
  }

  for (int k0 = 0; k0 < K; k0 += 32) {
#pragma unroll
    for (int it = 0; it < 2; ++it) {
      *(uint4*)(As + lo[it]) = *(const uint4*)(ap[it] + k0);
      *(uint4*)(Bs + lo[it]) = *(const uint4*)(bp[it] + k0);
    }
    __syncthreads();

    bf16x8 af[4], bfv[4];
#pragma unroll
    for (int i = 0; i < 4; ++i)
      af[i] = *(const bf16x8*)(As + (wm * 64 + i * 16 + fr) * 40 + fk);
#pragma unroll
    for (int j = 0; j < 4; ++j)
      bfv[j] = *(const bf16x8*)(Bs + (wn * 64 + j * 16 + fr) * 40 + fk);
#pragma unroll
    for (int i = 0; i < 4; ++i)
#pragma unroll
      for (int j = 0; j < 4; ++j)
        acc[i][j] = __builtin_amdgcn_mfma_f32_16x16x32_bf16(af[i], bfv[j], acc[i][j], 0, 0, 0);
    __syncthreads();
  }

  // epilogue: C/D layout col=lane&15, row=(lane>>4)*4+reg  [m89/m91-verified]
  const int rquad = (lane >> 4) * 4;
  const int cidx = lane & 15;
#pragma unroll
  for (int j = 0; j < 4; ++j) {
    int col = n0 + wn * 64 + j * 16 + cidx;
    float bv = bi[col];
#pragma unroll
    for (int i = 0; i < 4; ++i) {
      int rl = m0 + wm * 64 + i * 16 + rquad;
#pragma unroll
      for (int r = 0; r < 4; ++r) {
        if (rl + r < m_cnt) {
          float v = acc[i][j][r] + bv;
          if (RELU) v = fmaxf(v, 0.f);
          C[(size_t)(m_start + rl + r) * ldc + col] = f2bf(v);
        }
      }
    }
  }
}

// ---------------- atomic-free command bucketing -------------------------------
// 512 waves over BB; wavecnt[c][wid] via ballot (no atomics)
__global__ void k_count(const int* __restrict__ cmd, int* __restrict__ wavecnt) {
  int i = blockIdx.x * 256 + threadIdx.x;
  int c = cmd[i];
  int wid = i >> 6;
  int lane = threadIdx.x & 63;
#pragma unroll
  for (int cv = 0; cv < NCMD; ++cv) {
    unsigned long long m = __ballot(c == cv);
    if (lane == 0) wavecnt[cv * 512 + wid] = __popcll(m);
  }
}
// one block, 256 threads: wave c scans command c's 512 counts
__global__ void k_scan(const int* __restrict__ wavecnt, int* __restrict__ wavebase,
                       int* __restrict__ offs /*[5]*/) {
  __shared__ int tot[NCMD];
  __shared__ int soffs[NCMD + 1];
  int t = threadIdx.x, c = t >> 6, lane = t & 63;
  int v[8]; int s = 0;
#pragma unroll
  for (int q = 0; q < 8; ++q) { v[q] = wavecnt[c * 512 + lane * 8 + q]; s += v[q]; }
  int p = s;
#pragma unroll
  for (int m = 1; m < 64; m <<= 1) { int o = __shfl_up(p, m, 64); if (lane >= m) p += o; }
  int excl = p - s;
  if (lane == 63) tot[c] = p;
  __syncthreads();
  if (t == 0) {
    int o = 0;
    for (int e = 0; e < NCMD; ++e) { soffs[e] = o; o += tot[e]; }
    soffs[NCMD] = o;
    for (int e = 0; e <= NCMD; ++e) offs[e] = soffs[e];
  }
  __syncthreads();
  int base = soffs[c] + excl;
#pragma unroll
  for (int q = 0; q < 8; ++q) { wavebase[c * 512 + lane * 8 + q] = base; base += v[q]; }
}
__global__ void k_place(const int* __restrict__ cmd, const int* __restrict__ wavebase,
                        int* __restrict__ perm) {
  int i = blockIdx.x * 256 + threadIdx.x;
  int c = cmd[i];
  int wid = i >> 6, lane = threadIdx.x & 63;
  int rank = 0, base = 0;
#pragma unroll
  for (int cv = 0; cv < NCMD; ++cv) {
    unsigned long long m = __ballot(c == cv);
    if (c == cv) {
      rank = __popcll(m & ((1ull << lane) - 1ull));
      base = wavebase[cv * 512 + wid];
    }
  }
  perm[base + rank] = i;
}

// ---------------- v_p = h2 @ sp_w3 + b  (K=256, one wave per row) -------------
__global__ void k_vp(const unsigned short* __restrict__ h, const float* __restrict__ w,
                     const float* __restrict__ b, float* __restrict__ out) {
  int t = threadIdx.x;
  int row = blockIdx.x * 4 + (t >> 6);
  int lane = t & 63;
  int k = lane * 4;
  ushort4 hv = *(const ushort4*)(h + (size_t)row * CTRL_H + k);
  float4 wv = *(const float4*)(w + k);
  float a = bf2f(hv.x) * wv.x + bf2f(hv.y) * wv.y + bf2f(hv.z) * wv.z + bf2f(hv.w) * wv.w;
#pragma unroll
  for (int m = 32; m; m >>= 1) a += __shfl_xor(a, m, 64);
  if (lane == 0) out[row] = a + b[0];
}

// ------- actions: a = h2 @ ctrl_w3[e] + b3[e]; activations; scatter back ------
__global__ void k_act(const unsigned short* __restrict__ h, const int* __restrict__ perm,
                      const int* __restrict__ offs, const float* __restrict__ w3,
                      const float* __restrict__ b3, float* __restrict__ out) {
  int t = threadIdx.x;
  int p = blockIdx.x * 4 + (t >> 6);
  int lane = t & 63;
  int e = (p >= offs[1]) + (p >= offs[2]) + (p >= offs[3]);
  int orig = perm[p];
  int k = lane * 4;
  ushort4 hv = *(const ushort4*)(h + (size_t)p * CTRL_H + k);
  float hh[4] = { bf2f(hv.x), bf2f(hv.y), bf2f(hv.z), bf2f(hv.w) };
  const float* wp = w3 + ((size_t)e * CTRL_H + k) * 3;
  float a0 = 0.f, a1 = 0.f, a2 = 0.f;
#pragma unroll
  for (int q = 0; q < 4; ++q) {
    a0 = fmaf(hh[q], wp[q * 3 + 0], a0);
    a1 = fmaf(hh[q], wp[q * 3 + 1], a1);
    a2 = fmaf(hh[q], wp[q * 3 + 2], a2);
  }
#pragma unroll
  for (int m = 32; m; m >>= 1) {
    a0 += __shfl_xor(a0, m, 64);
    a1 += __shfl_xor(a1, m, 64);
    a2 += __shfl_xor(a2, m, 64);
  }
  if (lane == 0) {
    a0 += b3[e * 3 + 0]; a1 += b3[e * 3 + 1]; a2 += b3[e * 3 + 2];
    out[BB + orig]     = 1.f / (1.f + __expf(-a0));   // throttle = sigmoid(a0)
    out[2 * BB + orig] = 1.f / (1.f + __expf(-a2));   // brake    = sigmoid(a2)
    out[3 * BB + orig] = tanhf(a1);                   // steering = tanh(a1)
  }
}

static inline size_t align256(size_t x) { return (x + 255) & ~(size_t)255; }

extern "C" void kernel_launch(void* const* d_in, const int* in_sizes, int n_in,
                              void* d_out, int out_size, void* d_ws, size_t ws_size,
                              hipStream_t stream) {
  const float* feat   = (const float*)d_in[0];
  const float* speed  = (const float*)d_in[1];
  const int*   command= (const int*)d_in[2];
  const float* ms_w1  = (const float*)d_in[3];
  const float* ms_b1  = (const float*)d_in[4];
  const float* ms_w2  = (const float*)d_in[5];
  const float* ms_b2  = (const float*)d_in[6];
  const float* ms_w3  = (const float*)d_in[7];
  const float* ms_b3  = (const float*)d_in[8];
  const float* sp_w1  = (const float*)d_in[9];
  const float* sp_b1  = (const float*)d_in[10];
  const float* sp_w2  = (const float*)d_in[11];
  const float* sp_b2  = (const float*)d_in[12];
  const float* sp_w3  = (const float*)d_in[13];
  const float* sp_b3  = (const float*)d_in[14];
  const float* join_w = (const float*)d_in[15];
  const float* join_b = (const float*)d_in[16];
  const float* ctrl_w1= (const float*)d_in[17];
  const float* ctrl_b1= (const float*)d_in[18];
  const float* ctrl_w2= (const float*)d_in[19];
  const float* ctrl_b2= (const float*)d_in[20];
  const float* ctrl_w3= (const float*)d_in[21];
  const float* ctrl_b3= (const float*)d_in[22];
  float* out = (float*)d_out;

  char* ws = (char*)d_ws;
  size_t off = 0;
  auto alloc = [&](size_t bytes) -> char* { char* p = ws + off; off = align256(off + bytes); return p; };

  unsigned short* ajoin  = (unsigned short*)alloc((size_t)BB * 640 * 2);  // [B,640] bf16
  unsigned short* joined = (unsigned short*)alloc((size_t)BB * 512 * 2);  // [B,512] bf16
  unsigned short* msh1   = joined;                                        // alias (dead before joined)
  unsigned short* msh2   = joined + (size_t)BB * SPD_H;
  unsigned short* sph1   = (unsigned short*)alloc((size_t)BB * 256 * 2);  // reused as ch1
  unsigned short* sph2   = (unsigned short*)alloc((size_t)BB * 256 * 2);  // reused as ch2
  unsigned short* wtp    = (unsigned short*)alloc(1343488ull * 2);
  int* perm    = (int*)alloc((size_t)BB * 4);
  int* cnt     = (int*)alloc(64);        // offs[5] at cnt+4
  int* wavecnt = (int*)alloc(4 * 512 * 4);
  int* wavebase= (int*)alloc(4 * 512 * 4);

  unsigned short* ms_w2t  = wtp;             // [128][128]
  unsigned short* ms_w3t  = wtp + 16384;     // [128][128]
  unsigned short* sp_w1t  = wtp + 32768;     // [256][512]
  unsigned short* sp_w2t  = wtp + 163840;    // [256][256]
  unsigned short* join_wt = wtp + 229376;    // [512][640]
  unsigned short* c_w1t   = wtp + 557056;    // [4][256][512]
  unsigned short* c_w2t   = wtp + 1081344;   // [4][256][256]

  WSegs S;
  S.s[0] = { ms_w2, ms_w2t, 128, 128 };
  S.s[1] = { ms_w3, ms_w3t, 128, 128 };
  S.s[2] = { sp_w1, sp_w1t, 512, 256 };
  S.s[3] = { sp_w2, sp_w2t, 256, 256 };
  S.s[4] = { join_w, join_wt, 640, 512 };
  for (int e = 0; e < 4; ++e) S.s[5 + e] = { ctrl_w1 + (size_t)e * 512 * 256, c_w1t + (size_t)e * 131072, 512, 256 };
  for (int e = 0; e < 4; ++e) S.s[9 + e] = { ctrl_w2 + (size_t)e * 256 * 256, c_w2t + (size_t)e * 65536, 256, 256 };

  k_wt<<<dim3(320, 13, 1), 256, 0, stream>>>(S);           // max tiles = join: 20*16=320
  k_convert_feat<<<(BB * 128) / 256, 256, 0, stream>>>(feat, ajoin);
  k_ms1<<<(BB * 32) / 256, 256, 0, stream>>>(speed, ms_w1, ms_b1, msh1);

  // ms: h2 = relu(h1 @ w2 + b2); v = h2 @ w3 + b3 -> A_join[:,512:640]
  k_gemm<true ><<<dim3(1, 256, 1), 256, 0, stream>>>(msh1, 128, nullptr, nullptr,
      ms_w2t, 0, ms_b2, 0, msh2, 128, BB, 128, 128);
  k_gemm<false><<<dim3(1, 256, 1), 256, 0, stream>>>(msh2, 128, nullptr, nullptr,
      ms_w3t, 0, ms_b3, 0, ajoin + 512, 640, BB, 128, 128);

  // speed-pred branch
  k_gemm<true ><<<dim3(2, 256, 1), 256, 0, stream>>>(ajoin, 640, nullptr, nullptr,
      sp_w1t, 0, sp_b1, 0, sph1, 256, BB, 256, 512);
  k_gemm<true ><<<dim3(2, 256, 1), 256, 0, stream>>>(sph1, 256, nullptr, nullptr,
      sp_w2t, 0, sp_b2, 0, sph2, 256, BB, 256, 256);
  k_vp<<<BB / 4, 256, 0, stream>>>(sph2, sp_w3, sp_b3, out);

  // join: joined = A_join @ join_w + join_b
  k_gemm<false><<<dim3(4, 256, 1), 256, 0, stream>>>(ajoin, 640, nullptr, nullptr,
      join_wt, 0, join_b, 0, joined, 512, BB, 512, 640);

  // bucket by command (atomic-free)
  k_count<<<BB / 256, 256, 0, stream>>>(command, wavecnt);
  k_scan<<<1, 256, 0, stream>>>(wavecnt, wavebase, cnt + 4);
  k_place<<<BB / 256, 256, 0, stream>>>(command, wavebase, perm);

  // control heads (grouped, only selected expert per sample)
  k_gemm<true ><<<dim3(2, 256, 4), 256, 0, stream>>>(joined, 512, perm, cnt + 4,
      c_w1t, 131072, ctrl_b1, 256, sph1 /*ch1*/, 256, BB, 256, 512);
  k_gemm<true ><<<dim3(2, 256, 4), 256, 0, stream>>>(sph1, 256, nullptr, cnt + 4,
      c_w2t, 65536, ctrl_b2, 256, sph2 /*ch2*/, 256, BB, 256, 256);
  k_act<<<BB / 4, 256, 0, stream>>>(sph2, perm, cnt + 4, ctrl_w3, ctrl_b3, out);
}

// Round 3
// 354.507 us; speedup vs baseline: 1.5581x; 1.0148x over previous
//
#include <hip/hip_runtime.h>
#include <hip/hip_bf16.h>
#include <stdint.h>
#include <math.h>

#define BB 32768
#define FEAT 512
#define SPD_H 128
#define CTRL_H 256
#define NCMD 4

typedef __attribute__((ext_vector_type(8))) short bf16x8;
typedef __attribute__((ext_vector_type(4))) float f32x4;

__device__ __forceinline__ unsigned short f2bf(float f) {
  union { float f; uint32_t u; } v; v.f = f;
  uint32_t u = v.u;
  return (unsigned short)((u + 0x7fffu + ((u >> 16) & 1u)) >> 16); // RNE
}
__device__ __forceinline__ float bf2f(unsigned short h) {
  union { uint32_t u; float f; } v; v.u = ((uint32_t)h) << 16; return v.f;
}

// async global->LDS, 16B per lane; LDS dest = wave-uniform base + lane*16
__device__ __forceinline__ void async16(const unsigned short* g, unsigned short* l) {
  __builtin_amdgcn_global_load_lds(
      (const __attribute__((address_space(1))) unsigned int*)g,
      (__attribute__((address_space(3))) unsigned int*)l, 16, 0, 0);
}

// ---------------- feat f32 -> bf16 into A_join[:, 0:512] (stride 640) ----------
__global__ void k_convert_feat(const float* __restrict__ feat,
                               unsigned short* __restrict__ ajoin) {
  int idx = blockIdx.x * 256 + threadIdx.x;       // over BB*128
  int i = idx >> 7;
  int j4 = (idx & 127) << 2;
  float4 f = *(const float4*)(feat + (size_t)i * FEAT + j4);
  ushort4 o;
  o.x = f2bf(f.x); o.y = f2bf(f.y); o.z = f2bf(f.z); o.w = f2bf(f.w);
  *(ushort4*)(ajoin + (size_t)i * 640 + j4) = o;
}

// -- weight transpose+convert: W[K,N] f32 -> Wt[N,K] bf16 (dst row stride ldd) --
struct WSeg { const float* src; unsigned short* dst; int K; int N; int ldd; };
struct WSegs { WSeg s[13]; };
__global__ void k_wt(WSegs segs) {
  WSeg sg = segs.s[blockIdx.y];
  int tkx = sg.K >> 5, tnx = sg.N >> 5;
  int tile = blockIdx.x;
  if (tile >= tkx * tnx) return;
  int tn = tile / tkx;
  int tk = tile - tn * tkx;
  int k0 = tk * 32, n0 = tn * 32;
  __shared__ float tb[32][33];
  int tx = threadIdx.x & 31, ty = threadIdx.x >> 5;   // ty 0..7
#pragma unroll
  for (int j = 0; j < 4; ++j)
    tb[ty + j * 8][tx] = sg.src[(size_t)(k0 + ty + j * 8) * sg.N + n0 + tx];
  __syncthreads();
#pragma unroll
  for (int j = 0; j < 4; ++j)
    sg.dst[(size_t)(n0 + ty + j * 8) * sg.ldd + k0 + tx] = f2bf(tb[tx][ty + j * 8]);
}

// ---------------- ms layer1: h1[i][j] = relu(speed[i]*w1[j] + b1[j]) ----------
__global__ void k_ms1(const float* __restrict__ speed, const float* __restrict__ w1,
                      const float* __restrict__ b1, unsigned short* __restrict__ h1) {
  int idx = blockIdx.x * 256 + threadIdx.x;       // over BB*32
  int i = idx >> 5;
  int j4 = (idx & 31) << 2;
  float s = speed[i];
  float4 w = *(const float4*)(w1 + j4);
  float4 b = *(const float4*)(b1 + j4);
  ushort4 o;
  o.x = f2bf(fmaxf(fmaf(s, w.x, b.x), 0.f));
  o.y = f2bf(fmaxf(fmaf(s, w.y, b.y), 0.f));
  o.z = f2bf(fmaxf(fmaf(s, w.z, b.z), 0.f));
  o.w = f2bf(fmaxf(fmaf(s, w.w, b.w), 0.f));
  *(ushort4*)(h1 + (size_t)i * SPD_H + j4) = o;
}

// ---------------- generic bf16 MFMA GEMM: C = act(A @ Wt^T + bias) ------------
// global_load_lds (16B) staging, BK=32, unpadded LDS (conflict-optimal for the
// b128 fragment pattern: every bank serves exactly 8x4B per read = min cycles).
// Optional column split: cols >= nsplit go to C2/ldc2 with forced ReLU.
template<bool RELU>
__launch_bounds__(256)
__global__ void k_gemm(const unsigned short* __restrict__ A, int lda,
                       const int* __restrict__ perm,
                       const int* __restrict__ seg,
                       const unsigned short* __restrict__ Wt, int wstride,
                       const float* __restrict__ bias, int bstride,
                       unsigned short* __restrict__ C, int ldc,
                       unsigned short* __restrict__ C2, int ldc2, int nsplit,
                       int M, int N, int K) {
  __shared__ unsigned short As[128 * 32];
  __shared__ unsigned short Bs[128 * 32];

  const int e = blockIdx.z;
  int m_start = 0, m_cnt = M;
  if (seg) { m_start = seg[e]; m_cnt = seg[e + 1] - m_start; }
  const int m0 = blockIdx.y * 128;
  if (m0 >= m_cnt) return;
  const int n0 = blockIdx.x * 128;
  const unsigned short* W = Wt + (size_t)e * wstride;
  const float* bi = bias + (size_t)e * bstride;

  const int t = threadIdx.x;
  const int w = t >> 6, lane = t & 63;
  const int wm = w & 1, wn = w >> 1;

  f32x4 acc[4][4];
#pragma unroll
  for (int i = 0; i < 4; ++i)
#pragma unroll
    for (int j = 0; j < 4; ++j)
#pragma unroll
      for (int r = 0; r < 4; ++r) acc[i][j][r] = 0.f;

  const int fr = lane & 15;
  const int fk = (lane >> 4) * 8;

  // staging addresses (k-invariant): wave w, inst it -> rows w*32+it*16+(lane>>2),
  // 16B segment (lane&3)*8 elems. LDS dest is wave-uniform + lane*16 by HW.
  const unsigned short* agp[2]; const unsigned short* bgp[2];
  unsigned short* al[2]; unsigned short* bl[2];
#pragma unroll
  for (int it = 0; it < 2; ++it) {
    int row = w * 32 + it * 16 + (lane >> 2);
    int seg8 = (lane & 3) * 8;
    int rl = m0 + row;
    if (rl >= m_cnt) rl = m_cnt - 1;
    int grow = perm ? perm[m_start + rl] : (m_start + rl);
    agp[it] = A + (size_t)grow * lda + seg8;
    bgp[it] = W + (size_t)(n0 + row) * K + seg8;
    al[it] = As + (w * 32 + it * 16) * 32;
    bl[it] = Bs + (w * 32 + it * 16) * 32;
  }

  for (int k0 = 0; k0 < K; k0 += 32) {
#pragma unroll
    for (int it = 0; it < 2; ++it) {
      async16(agp[it] + k0, al[it]);
      async16(bgp[it] + k0, bl[it]);
    }
    __syncthreads();

    bf16x8 af[4], bfv[4];
#pragma unroll
    for (int i = 0; i < 4; ++i)
      af[i] = *(const bf16x8*)(As + (wm * 64 + i * 16 + fr) * 32 + fk);
#pragma unroll
    for (int j = 0; j < 4; ++j)
      bfv[j] = *(const bf16x8*)(Bs + (wn * 64 + j * 16 + fr) * 32 + fk);
#pragma unroll
    for (int i = 0; i < 4; ++i)
#pragma unroll
      for (int j = 0; j < 4; ++j)
        acc[i][j] = __builtin_amdgcn_mfma_f32_16x16x32_bf16(af[i], bfv[j], acc[i][j], 0, 0, 0);
    __syncthreads();
  }

  // epilogue: C/D layout col=lane&15, row=(lane>>4)*4+reg  [m89/m91-verified]
  const int rquad = (lane >> 4) * 4;
  const int cidx = lane & 15;
#pragma unroll
  for (int j = 0; j < 4; ++j) {
    int col = n0 + wn * 64 + j * 16 + cidx;
    float bv = bi[col];
    unsigned short* cp = C; int ldcc = ldc; int ccol = col; bool rel = RELU;
    if (C2 && col >= nsplit) { cp = C2; ldcc = ldc2; ccol = col - nsplit; rel = true; }
#pragma unroll
    for (int i = 0; i < 4; ++i) {
      int rl = m0 + wm * 64 + i * 16 + rquad;
#pragma unroll
      for (int r = 0; r < 4; ++r) {
        if (rl + r < m_cnt) {
          float v = acc[i][j][r] + bv;
          if (rel) v = fmaxf(v, 0.f);
          cp[(size_t)(m_start + rl + r) * ldcc + ccol] = f2bf(v);
        }
      }
    }
  }
}

// ---------------- atomic-free command bucketing -------------------------------
__global__ void k_count(const int* __restrict__ cmd, int* __restrict__ wavecnt) {
  int i = blockIdx.x * 256 + threadIdx.x;
  int c = cmd[i];
  int wid = i >> 6;
  int lane = threadIdx.x & 63;
#pragma unroll
  for (int cv = 0; cv < NCMD; ++cv) {
    unsigned long long m = __ballot(c == cv);
    if (lane == 0) wavecnt[cv * 512 + wid] = __popcll(m);
  }
}
__global__ void k_scan(const int* __restrict__ wavecnt, int* __restrict__ wavebase,
                       int* __restrict__ offs /*[5]*/) {
  __shared__ int tot[NCMD];
  __shared__ int soffs[NCMD + 1];
  int t = threadIdx.x, c = t >> 6, lane = t & 63;
  int v[8]; int s = 0;
#pragma unroll
  for (int q = 0; q < 8; ++q) { v[q] = wavecnt[c * 512 + lane * 8 + q]; s += v[q]; }
  int p = s;
#pragma unroll
  for (int m = 1; m < 64; m <<= 1) { int o = __shfl_up(p, m, 64); if (lane >= m) p += o; }
  int excl = p - s;
  if (lane == 63) tot[c] = p;
  __syncthreads();
  if (t == 0) {
    int o = 0;
    for (int e = 0; e < NCMD; ++e) { soffs[e] = o; o += tot[e]; }
    soffs[NCMD] = o;
    for (int e = 0; e <= NCMD; ++e) offs[e] = soffs[e];
  }
  __syncthreads();
  int base = soffs[c] + excl;
#pragma unroll
  for (int q = 0; q < 8; ++q) { wavebase[c * 512 + lane * 8 + q] = base; base += v[q]; }
}
__global__ void k_place(const int* __restrict__ cmd, const int* __restrict__ wavebase,
                        int* __restrict__ perm) {
  int i = blockIdx.x * 256 + threadIdx.x;
  int c = cmd[i];
  int wid = i >> 6, lane = threadIdx.x & 63;
  int rank = 0, base = 0;
#pragma unroll
  for (int cv = 0; cv < NCMD; ++cv) {
    unsigned long long m = __ballot(c == cv);
    if (c == cv) {
      rank = __popcll(m & ((1ull << lane) - 1ull));
      base = wavebase[cv * 512 + wid];
    }
  }
  perm[base + rank] = i;
}

// ---------------- v_p = h2 @ sp_w3 + b  (K=256, one wave per row) -------------
__global__ void k_vp(const unsigned short* __restrict__ h, const float* __restrict__ w,
                     const float* __restrict__ b, float* __restrict__ out) {
  int t = threadIdx.x;
  int row = blockIdx.x * 4 + (t >> 6);
  int lane = t & 63;
  int k = lane * 4;
  ushort4 hv = *(const ushort4*)(h + (size_t)row * CTRL_H + k);
  float4 wv = *(const float4*)(w + k);
  float a = bf2f(hv.x) * wv.x + bf2f(hv.y) * wv.y + bf2f(hv.z) * wv.z + bf2f(hv.w) * wv.w;
#pragma unroll
  for (int m = 32; m; m >>= 1) a += __shfl_xor(a, m, 64);
  if (lane == 0) out[row] = a + b[0];
}

// ------- actions: a = h2 @ ctrl_w3[e] + b3[e]; activations; scatter back ------
__global__ void k_act(const unsigned short* __restrict__ h, const int* __restrict__ perm,
                      const int* __restrict__ offs, const float* __restrict__ w3,
                      const float* __restrict__ b3, float* __restrict__ out) {
  int t = threadIdx.x;
  int p = blockIdx.x * 4 + (t >> 6);
  int lane = t & 63;
  int e = (p >= offs[1]) + (p >= offs[2]) + (p >= offs[3]);
  int orig = perm[p];
  int k = lane * 4;
  ushort4 hv = *(const ushort4*)(h + (size_t)p * CTRL_H + k);
  float hh[4] = { bf2f(hv.x), bf2f(hv.y), bf2f(hv.z), bf2f(hv.w) };
  const float* wp = w3 + ((size_t)e * CTRL_H + k) * 3;
  float a0 = 0.f, a1 = 0.f, a2 = 0.f;
#pragma unroll
  for (int q = 0; q < 4; ++q) {
    a0 = fmaf(hh[q], wp[q * 3 + 0], a0);
    a1 = fmaf(hh[q], wp[q * 3 + 1], a1);
    a2 = fmaf(hh[q], wp[q * 3 + 2], a2);
  }
#pragma unroll
  for (int m = 32; m; m >>= 1) {
    a0 += __shfl_xor(a0, m, 64);
    a1 += __shfl_xor(a1, m, 64);
    a2 += __shfl_xor(a2, m, 64);
  }
  if (lane == 0) {
    a0 += b3[e * 3 + 0]; a1 += b3[e * 3 + 1]; a2 += b3[e * 3 + 2];
    out[BB + orig]     = 1.f / (1.f + __expf(-a0));   // throttle = sigmoid(a0)
    out[2 * BB + orig] = 1.f / (1.f + __expf(-a2));   // brake    = sigmoid(a2)
    out[3 * BB + orig] = tanhf(a1);                   // steering = tanh(a1)
  }
}

static inline size_t align256(size_t x) { return (x + 255) & ~(size_t)255; }

extern "C" void kernel_launch(void* const* d_in, const int* in_sizes, int n_in,
                              void* d_out, int out_size, void* d_ws, size_t ws_size,
                              hipStream_t stream) {
  const float* feat   = (const float*)d_in[0];
  const float* speed  = (const float*)d_in[1];
  const int*   command= (const int*)d_in[2];
  const float* ms_w1  = (const float*)d_in[3];
  const float* ms_b1  = (const float*)d_in[4];
  const float* ms_w2  = (const float*)d_in[5];
  const float* ms_b2  = (const float*)d_in[6];
  const float* ms_w3  = (const float*)d_in[7];
  const float* ms_b3  = (const float*)d_in[8];
  const float* sp_w1  = (const float*)d_in[9];
  const float* sp_b1  = (const float*)d_in[10];
  const float* sp_w2  = (const float*)d_in[11];
  const float* sp_b2  = (const float*)d_in[12];
  const float* sp_w3  = (const float*)d_in[13];
  const float* sp_b3  = (const float*)d_in[14];
  const float* join_w = (const float*)d_in[15];
  const float* join_b = (const float*)d_in[16];
  const float* ctrl_w1= (const float*)d_in[17];
  const float* ctrl_b1= (const float*)d_in[18];
  const float* ctrl_w2= (const float*)d_in[19];
  const float* ctrl_b2= (const float*)d_in[20];
  const float* ctrl_w3= (const float*)d_in[21];
  const float* ctrl_b3= (const float*)d_in[22];
  float* out = (float*)d_out;

  char* ws = (char*)d_ws;
  size_t off = 0;
  auto alloc = [&](size_t bytes) -> char* { char* p = ws + off; off = align256(off + bytes); return p; };

  unsigned short* ajoin  = (unsigned short*)alloc((size_t)BB * 640 * 2);  // [B,640] bf16
  unsigned short* joined = (unsigned short*)alloc((size_t)BB * 512 * 2);  // [B,512] bf16
  unsigned short* msh1   = joined;                                        // alias (dead before joined)
  unsigned short* msh2   = joined + (size_t)BB * SPD_H;
  unsigned short* sph1   = (unsigned short*)alloc((size_t)BB * 256 * 2);  // reused as ch1
  unsigned short* sph2   = (unsigned short*)alloc((size_t)BB * 256 * 2);  // reused as ch2
  unsigned short* wtp    = (unsigned short*)alloc(1376256ull * 2);
  int* perm    = (int*)alloc((size_t)BB * 4);
  int* cnt     = (int*)alloc(64);        // offs[5] at cnt+4
  int* wavecnt = (int*)alloc(4 * 512 * 4);
  int* wavebase= (int*)alloc(4 * 512 * 4);

  // combined join+sp1 weight: [768][640]; rows 0-511 join (K=640),
  // rows 512-767 sp_w1^T (K=512, cols 512-639 zeroed)
  unsigned short* wt_js   = wtp;               // 768*640 = 491520
  unsigned short* ms_w2t  = wtp + 491520;      // [128][128]
  unsigned short* ms_w3t  = wtp + 507904;      // [128][128]
  unsigned short* sp_w2t  = wtp + 524288;      // [256][256]
  unsigned short* c_w1t   = wtp + 589824;      // [4][256][512]
  unsigned short* c_w2t   = wtp + 1114112;     // [4][256][256]
  // combined bias [768] (float) for join+sp1
  float* b_js = (float*)alloc(768 * 4);

  WSegs S;
  S.s[0] = { join_w, wt_js, 640, 512, 640 };
  S.s[1] = { sp_w1, wt_js + 512 * 640, 512, 256, 640 };
  S.s[2] = { ms_w2, ms_w2t, 128, 128, 128 };
  S.s[3] = { ms_w3, ms_w3t, 128, 128, 128 };
  S.s[4] = { sp_w2, sp_w2t, 256, 256, 256 };
  for (int e = 0; e < 4; ++e) S.s[5 + e] = { ctrl_w1 + (size_t)e * 512 * 256, c_w1t + (size_t)e * 131072, 512, 256, 512 };
  for (int e = 0; e < 4; ++e) S.s[9 + e] = { ctrl_w2 + (size_t)e * 256 * 256, c_w2t + (size_t)e * 65536, 256, 256, 256 };

  hipMemsetAsync(wt_js, 0, 768 * 640 * 2, stream);   // zero-pad sp_w1 K tail
  hipMemcpyAsync(b_js, join_b, 512 * 4, hipMemcpyDeviceToDevice, stream);
  hipMemcpyAsync(b_js + 512, sp_b1, 256 * 4, hipMemcpyDeviceToDevice, stream);
  k_wt<<<dim3(320, 13, 1), 256, 0, stream>>>(S);           // max tiles = join: 20*16=320
  k_convert_feat<<<(BB * 128) / 256, 256, 0, stream>>>(feat, ajoin);
  k_ms1<<<(BB * 32) / 256, 256, 0, stream>>>(speed, ms_w1, ms_b1, msh1);

  // ms: h2 = relu(h1 @ w2 + b2); v = h2 @ w3 + b3 -> A_join[:,512:640]
  k_gemm<true ><<<dim3(1, 256, 1), 256, 0, stream>>>(msh1, 128, nullptr, nullptr,
      ms_w2t, 0, ms_b2, 0, msh2, 128, nullptr, 0, 1 << 30, BB, 128, 128);
  k_gemm<false><<<dim3(1, 256, 1), 256, 0, stream>>>(msh2, 128, nullptr, nullptr,
      ms_w3t, 0, ms_b3, 0, ajoin + 512, 640, nullptr, 0, 1 << 30, BB, 128, 128);

  // combined join + sp1: [joined | relu(sph1)] = ajoin @ wt_js^T + b_js
  k_gemm<false><<<dim3(6, 256, 1), 256, 0, stream>>>(ajoin, 640, nullptr, nullptr,
      wt_js, 0, b_js, 0, joined, 512, sph1, 256, 512, BB, 768, 640);

  // sp2 + v_p
  k_gemm<true ><<<dim3(2, 256, 1), 256, 0, stream>>>(sph1, 256, nullptr, nullptr,
      sp_w2t, 0, sp_b2, 0, sph2, 256, nullptr, 0, 1 << 30, BB, 256, 256);
  k_vp<<<BB / 4, 256, 0, stream>>>(sph2, sp_w3, sp_b3, out);

  // bucket by command (atomic-free)
  k_count<<<BB / 256, 256, 0, stream>>>(command, wavecnt);
  k_scan<<<1, 256, 0, stream>>>(wavecnt, wavebase, cnt + 4);
  k_place<<<BB / 256, 256, 0, stream>>>(command, wavebase, perm);

  // control heads (grouped, only selected expert per sample)
  k_gemm<true ><<<dim3(2, 256, 4), 256, 0, stream>>>(joined, 512, perm, cnt + 4,
      c_w1t, 131072, ctrl_b1, 256, sph1 /*ch1*/, 256, nullptr, 0, 1 << 30, BB, 256, 512);
  k_gemm<true ><<<dim3(2, 256, 4), 256, 0, stream>>>(sph1, 256, nullptr, cnt + 4,
      c_w2t, 65536, ctrl_b2, 256, sph2 /*ch2*/, 256, nullptr, 0, 1 << 30, BB, 256, 256);
  k_act<<<BB / 4, 256, 0, stream>>>(sph2, perm, cnt + 4, ctrl_w3, ctrl_b3, out);
}

// Round 6
// 315.588 us; speedup vs baseline: 1.7502x; 1.1233x over previous
//
#include <hip/hip_runtime.h>
#include <hip/hip_bf16.h>
#include <stdint.h>
#include <math.h>

#define BB 32768
#define FEAT 512
#define SPD_H 128
#define CTRL_H 256
#define NCMD 4

typedef __attribute__((ext_vector_type(8))) short bf16x8;
typedef __attribute__((ext_vector_type(4))) float f32x4;

__device__ __forceinline__ unsigned short f2bf(float f) {
  union { float f; uint32_t u; } v; v.f = f;
  uint32_t u = v.u;
  return (unsigned short)((u + 0x7fffu + ((u >> 16) & 1u)) >> 16); // RNE
}
__device__ __forceinline__ float bf2f(unsigned short h) {
  union { uint32_t u; float f; } v; v.u = ((uint32_t)h) << 16; return v.f;
}

// async global->LDS, 16B per lane; LDS dest = wave-uniform base + lane*16
__device__ __forceinline__ void async16(const unsigned short* g, unsigned short* l) {
  __builtin_amdgcn_global_load_lds(
      (const __attribute__((address_space(1))) unsigned int*)g,
      (__attribute__((address_space(3))) unsigned int*)l, 16, 0, 0);
}

// ---------------- feat f32 -> bf16 into A_join[:, 0:512] (stride 640) ----------
__global__ void k_convert_feat(const float* __restrict__ feat,
                               unsigned short* __restrict__ ajoin) {
  int idx = blockIdx.x * 256 + threadIdx.x;       // over BB*128
  int i = idx >> 7;
  int j4 = (idx & 127) << 2;
  float4 f = *(const float4*)(feat + (size_t)i * FEAT + j4);
  ushort4 o;
  o.x = f2bf(f.x); o.y = f2bf(f.y); o.z = f2bf(f.z); o.w = f2bf(f.w);
  *(ushort4*)(ajoin + (size_t)i * 640 + j4) = o;
}

// -- weight transpose+convert: W[K,N] f32 -> Wt[N,K] bf16 (dst row stride ldd) --
struct WSeg { const float* src; unsigned short* dst; int K; int N; int ldd; };
struct WSegs { WSeg s[13]; };
__global__ void k_wt(WSegs segs) {
  WSeg sg = segs.s[blockIdx.y];
  int tkx = sg.K >> 5, tnx = sg.N >> 5;
  int tile = blockIdx.x;
  if (tile >= tkx * tnx) return;
  int tn = tile / tkx;
  int tk = tile - tn * tkx;
  int k0 = tk * 32, n0 = tn * 32;
  __shared__ float tb[32][33];
  int tx = threadIdx.x & 31, ty = threadIdx.x >> 5;   // ty 0..7
#pragma unroll
  for (int j = 0; j < 4; ++j)
    tb[ty + j * 8][tx] = sg.src[(size_t)(k0 + ty + j * 8) * sg.N + n0 + tx];
  __syncthreads();
#pragma unroll
  for (int j = 0; j < 4; ++j)
    sg.dst[(size_t)(n0 + ty + j * 8) * sg.ldd + k0 + tx] = f2bf(tb[tx][ty + j * 8]);
}

// --------- fused measured-speed module: speed -> v, into ajoin[:,512:640] -----
// h1 = relu(s*w1+b1) computed in LDS; two 128x128 MFMA layers LDS-resident.
__launch_bounds__(256)
__global__ void k_ms(const float* __restrict__ speed,
                     const float* __restrict__ w1, const float* __restrict__ b1,
                     const unsigned short* __restrict__ w2t, const float* __restrict__ b2,
                     const unsigned short* __restrict__ w3t, const float* __restrict__ b3,
                     unsigned short* __restrict__ ajoin) {
  __shared__ unsigned short hw[128][136];   // padded activation tile
  __shared__ unsigned short Bs[128 * 32];
  const int m0 = blockIdx.x * 128;
  const int t = threadIdx.x;
  const int w = t >> 6, lane = t & 63;
  const int wm = w & 1, wn = w >> 1;
  const int fr = lane & 15, fk = (lane >> 4) * 8;
  const int rquad = (lane >> 4) * 4, cidx = lane & 15;

  // layer 1 (rank-1): hw = relu(speed * w1 + b1)
  {
    int r = t >> 1, half = t & 1;
    float s = speed[m0 + r];
#pragma unroll
    for (int c0 = 0; c0 < 64; c0 += 4) {
      int c = half * 64 + c0;
      float4 wv = *(const float4*)(w1 + c);
      float4 bv = *(const float4*)(b1 + c);
      hw[r][c + 0] = f2bf(fmaxf(fmaf(s, wv.x, bv.x), 0.f));
      hw[r][c + 1] = f2bf(fmaxf(fmaf(s, wv.y, bv.y), 0.f));
      hw[r][c + 2] = f2bf(fmaxf(fmaf(s, wv.z, bv.z), 0.f));
      hw[r][c + 3] = f2bf(fmaxf(fmaf(s, wv.w, bv.w), 0.f));
    }
  }
  __syncthreads();

  for (int layer = 0; layer < 2; ++layer) {
    const unsigned short* Wt = layer ? w3t : w2t;
    const float* bb = layer ? b3 : b2;
    f32x4 acc[4][4];
#pragma unroll
    for (int i = 0; i < 4; ++i)
#pragma unroll
      for (int j = 0; j < 4; ++j)
#pragma unroll
        for (int r = 0; r < 4; ++r) acc[i][j][r] = 0.f;

    for (int k0 = 0; k0 < 128; k0 += 32) {
#pragma unroll
      for (int it = 0; it < 2; ++it) {
        int row = w * 32 + it * 16 + (lane >> 2);
        async16(Wt + (size_t)row * 128 + k0 + (lane & 3) * 8,
                Bs + (w * 32 + it * 16) * 32);
      }
      __syncthreads();
      bf16x8 af[4], bfv[4];
#pragma unroll
      for (int i = 0; i < 4; ++i)
        af[i] = *(const bf16x8*)(&hw[wm * 64 + i * 16 + fr][k0 + fk]);
#pragma unroll
      for (int j = 0; j < 4; ++j)
        bfv[j] = *(const bf16x8*)(Bs + (wn * 64 + j * 16 + fr) * 32 + fk);
#pragma unroll
      for (int i = 0; i < 4; ++i)
#pragma unroll
        for (int j = 0; j < 4; ++j)
          acc[i][j] = __builtin_amdgcn_mfma_f32_16x16x32_bf16(af[i], bfv[j], acc[i][j], 0, 0, 0);
      __syncthreads();
    }
    // write result back into hw (bias; relu on layer0 only)
#pragma unroll
    for (int j = 0; j < 4; ++j) {
      int col = wn * 64 + j * 16 + cidx;
      float bv = bb[col];
#pragma unroll
      for (int i = 0; i < 4; ++i) {
        int row = wm * 64 + i * 16 + rquad;
#pragma unroll
        for (int r = 0; r < 4; ++r) {
          float v = acc[i][j][r] + bv;
          if (layer == 0) v = fmaxf(v, 0.f);
          hw[row + r][col] = f2bf(v);
        }
      }
    }
    __syncthreads();
  }
  // coalesced copy out: hw -> ajoin[:,512:640]
  {
    int r = t >> 1, half = t & 1;
#pragma unroll
    for (int c8 = 0; c8 < 8; ++c8)
      *(bf16x8*)(ajoin + (size_t)(m0 + r) * 640 + 512 + half * 64 + c8 * 8) =
          *(const bf16x8*)(&hw[r][half * 64 + c8 * 8]);
  }
}

// ---------------- generic bf16 MFMA GEMM with fused extras --------------------
// 1-D grid (XCD-swizzled): m_tile = gid&255, n_tile = gid>>8; z = expert.
// C = act(A @ Wt^T + bias); optional split at nsplit (block-level, 128-aligned).
// Epilogue: LDS-bounce -> coalesced 16B bf16 stores (C==null skips stores).
// NAUX>0: per-row dots of post-act value with aux_w -> atomicAdd into aux_out;
// the n0==0 block's wn==0 wave adds aux_b exactly once per row.
template<int NAUX>
__launch_bounds__(256)
__global__ void k_gemm(const unsigned short* __restrict__ A, int lda,
                       const int* __restrict__ perm,
                       const int* __restrict__ seg,
                       const unsigned short* __restrict__ Wt, int wstride,
                       const float* __restrict__ bias, int bstride,
                       unsigned short* __restrict__ C, int ldc,
                       unsigned short* __restrict__ C2, int ldc2, int nsplit,
                       const float* __restrict__ aux_w, int aux_wstride,
                       float* __restrict__ aux_out, const float* __restrict__ aux_b,
                       int relu_flag, int M, int K) {
  __shared__ unsigned short As[128 * 32];
  __shared__ unsigned short Bs[128 * 32];
  __shared__ float fscr[32][132];           // padded f32 bounce (16.5 KB)

  const int gid = blockIdx.x;
  const int mt = gid & 255;
  const int nt = gid >> 8;
  const int e = blockIdx.z;
  int m_start = 0, m_cnt = M;
  if (seg) { m_start = seg[e]; m_cnt = seg[e + 1] - m_start; }
  const int m0 = mt * 128;
  if (m0 >= m_cnt) return;
  const int n0 = nt * 128;
  const unsigned short* W = Wt + (size_t)e * wstride;
  const float* bi = bias + (size_t)e * bstride;

  const int t = threadIdx.x;
  const int w = t >> 6, lane = t & 63;
  const int wm = w & 1, wn = w >> 1;

  f32x4 acc[4][4];
#pragma unroll
  for (int i = 0; i < 4; ++i)
#pragma unroll
    for (int j = 0; j < 4; ++j)
#pragma unroll
      for (int r = 0; r < 4; ++r) acc[i][j][r] = 0.f;

  const int fr = lane & 15;
  const int fk = (lane >> 4) * 8;

  const unsigned short* agp[2]; const unsigned short* bgp[2];
  unsigned short* al[2]; unsigned short* bl[2];
#pragma unroll
  for (int it = 0; it < 2; ++it) {
    int row = w * 32 + it * 16 + (lane >> 2);
    int seg8 = (lane & 3) * 8;
    int rl = m0 + row;
    if (rl >= m_cnt) rl = m_cnt - 1;
    int grow = perm ? perm[m_start + rl] : (m_start + rl);
    agp[it] = A + (size_t)grow * lda + seg8;
    bgp[it] = W + (size_t)(n0 + row) * K + seg8;
    al[it] = As + (w * 32 + it * 16) * 32;
    bl[it] = Bs + (w * 32 + it * 16) * 32;
  }

  for (int k0 = 0; k0 < K; k0 += 32) {
#pragma unroll
    for (int it = 0; it < 2; ++it) {
      async16(agp[it] + k0, al[it]);
      async16(bgp[it] + k0, bl[it]);
    }
    __syncthreads();
    bf16x8 af[4], bfv[4];
#pragma unroll
    for (int i = 0; i < 4; ++i)
      af[i] = *(const bf16x8*)(As + (wm * 64 + i * 16 + fr) * 32 + fk);
#pragma unroll
    for (int j = 0; j < 4; ++j)
      bfv[j] = *(const bf16x8*)(Bs + (wn * 64 + j * 16 + fr) * 32 + fk);
#pragma unroll
    for (int i = 0; i < 4; ++i)
#pragma unroll
      for (int j = 0; j < 4; ++j)
        acc[i][j] = __builtin_amdgcn_mfma_f32_16x16x32_bf16(af[i], bfv[j], acc[i][j], 0, 0, 0);
    __syncthreads();
  }

  const int rquad = (lane >> 4) * 4;
  const int cidx = lane & 15;

  // block-level dest select (nsplit multiple of 128)
  unsigned short* cp; int ldcc, ccol0; bool rel = (relu_flag != 0);
  if (C2 && n0 >= nsplit) { cp = C2; ldcc = ldc2; ccol0 = n0 - nsplit; rel = true; }
  else { cp = C; ldcc = ldc; ccol0 = n0; }

  float bv[4];
#pragma unroll
  for (int j = 0; j < 4; ++j) bv[j] = bi[n0 + wn * 64 + j * 16 + cidx];

  // fused aux dots (v_p / action partials)
  if constexpr (NAUX > 0) {
    const bool add_bias = (aux_b && n0 == 0 && wn == 0);   // exactly once per row
    float aw[4][NAUX];
#pragma unroll
    for (int j = 0; j < 4; ++j) {
      int col = n0 + wn * 64 + j * 16 + cidx;
#pragma unroll
      for (int q = 0; q < NAUX; ++q)
        aw[j][q] = aux_w[(size_t)e * aux_wstride + col * NAUX + q];
    }
#pragma unroll
    for (int i = 0; i < 4; ++i) {
#pragma unroll
      for (int r = 0; r < 4; ++r) {
        float s[NAUX];
#pragma unroll
        for (int q = 0; q < NAUX; ++q) s[q] = 0.f;
#pragma unroll
        for (int j = 0; j < 4; ++j) {
          float v = acc[i][j][r] + bv[j];
          if (rel) v = fmaxf(v, 0.f);
#pragma unroll
          for (int q = 0; q < NAUX; ++q) s[q] = fmaf(v, aw[j][q], s[q]);
        }
#pragma unroll
        for (int q = 0; q < NAUX; ++q) {
          s[q] += __shfl_xor(s[q], 1, 64);
          s[q] += __shfl_xor(s[q], 2, 64);
          s[q] += __shfl_xor(s[q], 4, 64);
          s[q] += __shfl_xor(s[q], 8, 64);
        }
        int grow = m0 + wm * 64 + i * 16 + rquad + r;
        if ((lane & 15) == 0 && grow < m_cnt) {
#pragma unroll
          for (int q = 0; q < NAUX; ++q) {
            float add = s[q] + (add_bias ? aux_b[q] : 0.f);
            atomicAdd(&aux_out[(size_t)(m_start + grow) * NAUX + q], add);
          }
        }
      }
    }
  }

  if (!cp) return;

  // LDS-bounce epilogue: 4 chunks of 32 rows -> coalesced bf16 stores
#pragma unroll
  for (int c = 0; c < 4; ++c) {
    if (wm == (c >> 1)) {
#pragma unroll
      for (int j = 0; j < 4; ++j) {
#pragma unroll
        for (int ii = 0; ii < 2; ++ii) {
          int i = 2 * (c & 1) + ii;
          int lr = ii * 16 + rquad;
#pragma unroll
          for (int r = 0; r < 4; ++r) {
            float v = acc[i][j][r] + bv[j];
            if (rel) v = fmaxf(v, 0.f);
            fscr[lr + r][wn * 64 + j * 16 + cidx] = v;
          }
        }
      }
    }
    __syncthreads();
#pragma unroll
    for (int q = 0; q < 2; ++q) {
      int sg = t + 256 * q;                 // 0..511
      int lr = sg >> 4, cs = (sg & 15) * 8;
      int grow = m0 + c * 32 + lr;
      if (grow < m_cnt) {
        union { bf16x8 v; unsigned short u[8]; } pk;
#pragma unroll
        for (int x = 0; x < 8; ++x) pk.u[x] = f2bf(fscr[lr][cs + x]);
        *(bf16x8*)(cp + (size_t)(m_start + grow) * ldcc + ccol0 + cs) = pk.v;
      }
    }
    __syncthreads();
  }
}

// ---------------- atomic-free command bucketing -------------------------------
__global__ void k_count(const int* __restrict__ cmd, int* __restrict__ wavecnt) {
  int i = blockIdx.x * 256 + threadIdx.x;
  int c = cmd[i];
  int wid = i >> 6;
  int lane = threadIdx.x & 63;
#pragma unroll
  for (int cv = 0; cv < NCMD; ++cv) {
    unsigned long long m = __ballot(c == cv);
    if (lane == 0) wavecnt[cv * 512 + wid] = __popcll(m);
  }
}
__global__ void k_scan(const int* __restrict__ wavecnt, int* __restrict__ wavebase,
                       int* __restrict__ offs /*[5]*/) {
  __shared__ int tot[NCMD];
  __shared__ int soffs[NCMD + 1];
  int t = threadIdx.x, c = t >> 6, lane = t & 63;
  int v[8]; int s = 0;
#pragma unroll
  for (int q = 0; q < 8; ++q) { v[q] = wavecnt[c * 512 + lane * 8 + q]; s += v[q]; }
  int p = s;
#pragma unroll
  for (int m = 1; m < 64; m <<= 1) { int o = __shfl_up(p, m, 64); if (lane >= m) p += o; }
  int excl = p - s;
  if (lane == 63) tot[c] = p;
  __syncthreads();
  if (t == 0) {
    int o = 0;
    for (int e = 0; e < NCMD; ++e) { soffs[e] = o; o += tot[e]; }
    soffs[NCMD] = o;
    for (int e = 0; e <= NCMD; ++e) offs[e] = soffs[e];
  }
  __syncthreads();
  int base = soffs[c] + excl;
#pragma unroll
  for (int q = 0; q < 8; ++q) { wavebase[c * 512 + lane * 8 + q] = base; base += v[q]; }
}
// place also pre-seeds act_raw with per-expert bias b3
__global__ void k_place(const int* __restrict__ cmd, const int* __restrict__ wavebase,
                        int* __restrict__ perm, const float* __restrict__ b3,
                        float* __restrict__ act_raw) {
  int i = blockIdx.x * 256 + threadIdx.x;
  int c = cmd[i];
  int wid = i >> 6, lane = threadIdx.x & 63;
  int rank = 0, base = 0;
#pragma unroll
  for (int cv = 0; cv < NCMD; ++cv) {
    unsigned long long m = __ballot(c == cv);
    if (c == cv) {
      rank = __popcll(m & ((1ull << lane) - 1ull));
      base = wavebase[cv * 512 + wid];
    }
  }
  int p = base + rank;
  perm[p] = i;
  act_raw[p * 3 + 0] = b3[c * 3 + 0];
  act_raw[p * 3 + 1] = b3[c * 3 + 1];
  act_raw[p * 3 + 2] = b3[c * 3 + 2];
}

// ---------------- finish: activations + scatter back --------------------------
__global__ void k_finish(const float* __restrict__ act_raw, const int* __restrict__ perm,
                         float* __restrict__ out) {
  int p = blockIdx.x * 256 + threadIdx.x;
  int orig = perm[p];
  float a0 = act_raw[p * 3 + 0];
  float a1 = act_raw[p * 3 + 1];
  float a2 = act_raw[p * 3 + 2];
  out[BB + orig]     = 1.f / (1.f + __expf(-a0));   // throttle
  out[2 * BB + orig] = 1.f / (1.f + __expf(-a2));   // brake
  out[3 * BB + orig] = tanhf(a1);                   // steering
}

static inline size_t align256(size_t x) { return (x + 255) & ~(size_t)255; }

extern "C" void kernel_launch(void* const* d_in, const int* in_sizes, int n_in,
                              void* d_out, int out_size, void* d_ws, size_t ws_size,
                              hipStream_t stream) {
  const float* feat   = (const float*)d_in[0];
  const float* speed  = (const float*)d_in[1];
  const int*   command= (const int*)d_in[2];
  const float* ms_w1  = (const float*)d_in[3];
  const float* ms_b1  = (const float*)d_in[4];
  const float* ms_w2  = (const float*)d_in[5];
  const float* ms_b2  = (const float*)d_in[6];
  const float* ms_w3  = (const float*)d_in[7];
  const float* ms_b3  = (const float*)d_in[8];
  const float* sp_w1  = (const float*)d_in[9];
  const float* sp_b1  = (const float*)d_in[10];
  const float* sp_w2  = (const float*)d_in[11];
  const float* sp_b2  = (const float*)d_in[12];
  const float* sp_w3  = (const float*)d_in[13];
  const float* sp_b3  = (const float*)d_in[14];
  const float* join_w = (const float*)d_in[15];
  const float* join_b = (const float*)d_in[16];
  const float* ctrl_w1= (const float*)d_in[17];
  const float* ctrl_b1= (const float*)d_in[18];
  const float* ctrl_w2= (const float*)d_in[19];
  const float* ctrl_b2= (const float*)d_in[20];
  const float* ctrl_w3= (const float*)d_in[21];
  const float* ctrl_b3= (const float*)d_in[22];
  float* out = (float*)d_out;

  char* ws = (char*)d_ws;
  size_t off = 0;
  auto alloc = [&](size_t bytes) -> char* { char* p = ws + off; off = align256(off + bytes); return p; };

  unsigned short* ajoin  = (unsigned short*)alloc((size_t)BB * 640 * 2);  // [B,640] bf16
  unsigned short* joined = (unsigned short*)alloc((size_t)BB * 512 * 2);  // [B,512] bf16
  unsigned short* sph1   = (unsigned short*)alloc((size_t)BB * 256 * 2);
  unsigned short* ch1    = (unsigned short*)alloc((size_t)BB * 256 * 2);
  unsigned short* wtp    = (unsigned short*)alloc(1376256ull * 2);
  int* perm    = (int*)alloc((size_t)BB * 4);
  int* cnt     = (int*)alloc(64);        // offs[5] at cnt+4
  int* wavecnt = (int*)alloc(4 * 512 * 4);
  int* wavebase= (int*)alloc(4 * 512 * 4);
  float* act_raw = (float*)alloc((size_t)BB * 3 * 4);
  float* b_js    = (float*)alloc(768 * 4);

  unsigned short* wt_js   = wtp;               // [768][640]
  unsigned short* ms_w2t  = wtp + 491520;      // [128][128]
  unsigned short* ms_w3t  = wtp + 507904;      // [128][128]
  unsigned short* sp_w2t  = wtp + 524288;      // [256][256]
  unsigned short* c_w1t   = wtp + 589824;      // [4][256][512]
  unsigned short* c_w2t   = wtp + 1114112;     // [4][256][256]

  WSegs S;
  S.s[0] = { join_w, wt_js, 640, 512, 640 };
  S.s[1] = { sp_w1, wt_js + 512 * 640, 512, 256, 640 };
  S.s[2] = { ms_w2, ms_w2t, 128, 128, 128 };
  S.s[3] = { ms_w3, ms_w3t, 128, 128, 128 };
  S.s[4] = { sp_w2, sp_w2t, 256, 256, 256 };
  for (int e = 0; e < 4; ++e) S.s[5 + e] = { ctrl_w1 + (size_t)e * 512 * 256, c_w1t + (size_t)e * 131072, 512, 256, 512 };
  for (int e = 0; e < 4; ++e) S.s[9 + e] = { ctrl_w2 + (size_t)e * 256 * 256, c_w2t + (size_t)e * 65536, 256, 256, 256 };

  (void)hipMemsetAsync(wt_js, 0, 768 * 640 * 2, stream);   // zero-pad sp_w1 K tail
  (void)hipMemsetAsync(out, 0, (size_t)BB * 4, stream);    // v_p accumulator base
  (void)hipMemcpyAsync(b_js, join_b, 512 * 4, hipMemcpyDeviceToDevice, stream);
  (void)hipMemcpyAsync(b_js + 512, sp_b1, 256 * 4, hipMemcpyDeviceToDevice, stream);
  k_wt<<<dim3(320, 13, 1), 256, 0, stream>>>(S);
  k_convert_feat<<<(BB * 128) / 256, 256, 0, stream>>>(feat, ajoin);
  k_ms<<<256, 256, 0, stream>>>(speed, ms_w1, ms_b1, ms_w2t, ms_b2, ms_w3t, ms_b3, ajoin);

  // bucket by command (atomic-free) + pre-seed act_raw with b3
  k_count<<<BB / 256, 256, 0, stream>>>(command, wavecnt);
  k_scan<<<1, 256, 0, stream>>>(wavecnt, wavebase, cnt + 4);
  k_place<<<BB / 256, 256, 0, stream>>>(command, wavebase, perm, ctrl_b3, act_raw);

  // combined join + sp1: [joined | relu(sph1)] = ajoin @ wt_js^T + b_js
  k_gemm<0><<<256 * 6, 256, 0, stream>>>(ajoin, 640, nullptr, nullptr,
      wt_js, 0, b_js, 0, joined, 512, sph1, 256, 512,
      nullptr, 0, nullptr, nullptr, 0, BB, 640);

  // sp2 (+ fused v_p dot -> out[0:BB])
  k_gemm<1><<<256 * 2, 256, 0, stream>>>(sph1, 256, nullptr, nullptr,
      sp_w2t, 0, sp_b2, 0, nullptr, 0, nullptr, 0, 1 << 30,
      sp_w3, 0, out, sp_b3, 1, BB, 256);

  // ctrl1 (grouped, gathered rows)
  k_gemm<0><<<dim3(256 * 2, 1, 4), 256, 0, stream>>>(joined, 512, perm, cnt + 4,
      c_w1t, 131072, ctrl_b1, 256, ch1, 256, nullptr, 0, 1 << 30,
      nullptr, 0, nullptr, nullptr, 1, BB, 512);

  // ctrl2 (+ fused 3-dot action -> act_raw)
  k_gemm<3><<<dim3(256 * 2, 1, 4), 256, 0, stream>>>(ch1, 256, nullptr, cnt + 4,
      c_w2t, 65536, ctrl_b2, 256, nullptr, 0, nullptr, 0, 1 << 30,
      ctrl_w3, 256 * 3, act_raw, nullptr, 1, BB, 256);

  k_finish<<<BB / 256, 256, 0, stream>>>(act_raw, perm, out);
}

// Round 7
// 267.831 us; speedup vs baseline: 2.0623x; 1.1783x over previous
//
#include <hip/hip_runtime.h>
#include <hip/hip_bf16.h>
#include <stdint.h>
#include <math.h>

#define BB 32768
#define FEAT 512
#define SPD_H 128
#define CTRL_H 256
#define NCMD 4

typedef __attribute__((ext_vector_type(8))) short bf16x8;
typedef __attribute__((ext_vector_type(4))) float f32x4;

__device__ __forceinline__ unsigned short f2bf(float f) {
  union { float f; uint32_t u; } v; v.f = f;
  uint32_t u = v.u;
  return (unsigned short)((u + 0x7fffu + ((u >> 16) & 1u)) >> 16); // RNE
}

// async global->LDS, 16B per lane; LDS dest = wave-uniform base + lane*16
__device__ __forceinline__ void async16(const unsigned short* g, unsigned short* l) {
  __builtin_amdgcn_global_load_lds(
      (const __attribute__((address_space(1))) unsigned int*)g,
      (__attribute__((address_space(3))) unsigned int*)l, 16, 0, 0);
}

// ---------------- fused prep: feat convert + all weight transposes + b_js -----
struct WSeg { const float* src; unsigned short* dst; int K; int N; int ldd; };
struct PrepArgs {
  WSeg s[13];
  int start[14];            // cumulative tile offsets per seg
  const float* join_b; const float* sp_b1; float* b_js;
  const float* feat; unsigned short* ajoin;
};
__global__ void k_prep(PrepArgs a) {
  int bx = blockIdx.x, t = threadIdx.x;
  if (bx < 16384) {          // feat f32 -> bf16 into ajoin[:,0:512] (stride 640)
    int idx = bx * 256 + t;
    int i = idx >> 7;
    int j4 = (idx & 127) << 2;
    float4 f = *(const float4*)(a.feat + (size_t)i * FEAT + j4);
    ushort4 o;
    o.x = f2bf(f.x); o.y = f2bf(f.y); o.z = f2bf(f.z); o.w = f2bf(f.w);
    *(ushort4*)(a.ajoin + (size_t)i * 640 + j4) = o;
    return;
  }
  int rel = bx - 16384;
  if (rel >= a.start[13]) {  // last block: assemble b_js = [join_b | sp_b1]
    for (int i = t; i < 768; i += 256)
      a.b_js[i] = (i < 512) ? a.join_b[i] : a.sp_b1[i - 512];
    return;
  }
  int si = 0;
  while (rel >= a.start[si + 1]) ++si;
  WSeg sg = a.s[si];
  int tile = rel - a.start[si];
  int tkx = sg.K >> 5;
  int tn = tile / tkx;
  int tk = tile - tn * tkx;
  int k0 = tk * 32, n0 = tn * 32;
  __shared__ float tb[32][33];
  int tx = t & 31, ty = t >> 5;
#pragma unroll
  for (int j = 0; j < 4; ++j)
    tb[ty + j * 8][tx] = sg.src[(size_t)(k0 + ty + j * 8) * sg.N + n0 + tx];
  __syncthreads();
#pragma unroll
  for (int j = 0; j < 4; ++j)
    sg.dst[(size_t)(n0 + ty + j * 8) * sg.ldd + k0 + tx] = f2bf(tb[tx][ty + j * 8]);
}

// --------- fused measured-speed module: speed -> v, into ajoin[:,512:640] -----
__launch_bounds__(256)
__global__ void k_ms(const float* __restrict__ speed,
                     const float* __restrict__ w1, const float* __restrict__ b1,
                     const unsigned short* __restrict__ w2t, const float* __restrict__ b2,
                     const unsigned short* __restrict__ w3t, const float* __restrict__ b3,
                     unsigned short* __restrict__ ajoin) {
  __shared__ unsigned short hw[128][136];
  __shared__ unsigned short Bs[128 * 32];
  const int m0 = blockIdx.x * 128;
  const int t = threadIdx.x;
  const int w = t >> 6, lane = t & 63;
  const int wm = w & 1, wn = w >> 1;
  const int fr = lane & 15, fk = (lane >> 4) * 8;
  const int rquad = (lane >> 4) * 4, cidx = lane & 15;

  {
    int r = t >> 1, half = t & 1;
    float s = speed[m0 + r];
#pragma unroll
    for (int c0 = 0; c0 < 64; c0 += 4) {
      int c = half * 64 + c0;
      float4 wv = *(const float4*)(w1 + c);
      float4 bv = *(const float4*)(b1 + c);
      hw[r][c + 0] = f2bf(fmaxf(fmaf(s, wv.x, bv.x), 0.f));
      hw[r][c + 1] = f2bf(fmaxf(fmaf(s, wv.y, bv.y), 0.f));
      hw[r][c + 2] = f2bf(fmaxf(fmaf(s, wv.z, bv.z), 0.f));
      hw[r][c + 3] = f2bf(fmaxf(fmaf(s, wv.w, bv.w), 0.f));
    }
  }
  __syncthreads();

  for (int layer = 0; layer < 2; ++layer) {
    const unsigned short* Wt = layer ? w3t : w2t;
    const float* bb = layer ? b3 : b2;
    f32x4 acc[4][4];
#pragma unroll
    for (int i = 0; i < 4; ++i)
#pragma unroll
      for (int j = 0; j < 4; ++j)
#pragma unroll
        for (int r = 0; r < 4; ++r) acc[i][j][r] = 0.f;

    for (int k0 = 0; k0 < 128; k0 += 32) {
#pragma unroll
      for (int it = 0; it < 2; ++it) {
        int row = w * 32 + it * 16 + (lane >> 2);
        async16(Wt + (size_t)row * 128 + k0 + (lane & 3) * 8,
                Bs + (w * 32 + it * 16) * 32);
      }
      __syncthreads();
      bf16x8 af[4], bfv[4];
#pragma unroll
      for (int i = 0; i < 4; ++i)
        af[i] = *(const bf16x8*)(&hw[wm * 64 + i * 16 + fr][k0 + fk]);
#pragma unroll
      for (int j = 0; j < 4; ++j)
        bfv[j] = *(const bf16x8*)(Bs + (wn * 64 + j * 16 + fr) * 32 + fk);
#pragma unroll
      for (int i = 0; i < 4; ++i)
#pragma unroll
        for (int j = 0; j < 4; ++j)
          acc[i][j] = __builtin_amdgcn_mfma_f32_16x16x32_bf16(af[i], bfv[j], acc[i][j], 0, 0, 0);
      __syncthreads();
    }
#pragma unroll
    for (int j = 0; j < 4; ++j) {
      int col = wn * 64 + j * 16 + cidx;
      float bv = bb[col];
#pragma unroll
      for (int i = 0; i < 4; ++i) {
        int row = wm * 64 + i * 16 + rquad;
#pragma unroll
        for (int r = 0; r < 4; ++r) {
          float v = acc[i][j][r] + bv;
          if (layer == 0) v = fmaxf(v, 0.f);
          hw[row + r][col] = f2bf(v);
        }
      }
    }
    __syncthreads();
  }
  {
    int r = t >> 1, half = t & 1;
#pragma unroll
    for (int c8 = 0; c8 < 8; ++c8)
      *(bf16x8*)(ajoin + (size_t)(m0 + r) * 640 + 512 + half * 64 + c8 * 8) =
          *(const bf16x8*)(&hw[r][half * 64 + c8 * 8]);
  }
}

// ---------------- 128x128 bf16 MFMA GEMM, bounce epilogue ---------------------
// 1-D grid (XCD-friendly): m_tile = gid&255, n_tile = gid>>8; z = expert.
__launch_bounds__(256)
__global__ void k_gemm(const unsigned short* __restrict__ A, int lda,
                       const int* __restrict__ perm,
                       const int* __restrict__ seg,
                       const unsigned short* __restrict__ Wt, int wstride,
                       const float* __restrict__ bias, int bstride,
                       unsigned short* __restrict__ C, int ldc,
                       unsigned short* __restrict__ C2, int ldc2, int nsplit,
                       int relu_flag, int M, int K) {
  __shared__ unsigned short As[128 * 32];
  __shared__ unsigned short Bs[128 * 32];
  __shared__ float fscr[32][132];

  const int gid = blockIdx.x;
  const int mt = gid & 255;
  const int nt = gid >> 8;
  const int e = blockIdx.z;
  int m_start = 0, m_cnt = M;
  if (seg) { m_start = seg[e]; m_cnt = seg[e + 1] - m_start; }
  const int m0 = mt * 128;
  if (m0 >= m_cnt) return;
  const int n0 = nt * 128;
  const unsigned short* W = Wt + (size_t)e * wstride;
  const float* bi = bias + (size_t)e * bstride;

  const int t = threadIdx.x;
  const int w = t >> 6, lane = t & 63;
  const int wm = w & 1, wn = w >> 1;

  f32x4 acc[4][4];
#pragma unroll
  for (int i = 0; i < 4; ++i)
#pragma unroll
    for (int j = 0; j < 4; ++j)
#pragma unroll
      for (int r = 0; r < 4; ++r) acc[i][j][r] = 0.f;

  const int fr = lane & 15;
  const int fk = (lane >> 4) * 8;

  const unsigned short* agp[2]; const unsigned short* bgp[2];
  unsigned short* al[2]; unsigned short* bl[2];
#pragma unroll
  for (int it = 0; it < 2; ++it) {
    int row = w * 32 + it * 16 + (lane >> 2);
    int seg8 = (lane & 3) * 8;
    int rl = m0 + row;
    if (rl >= m_cnt) rl = m_cnt - 1;
    int grow = perm ? perm[m_start + rl] : (m_start + rl);
    agp[it] = A + (size_t)grow * lda + seg8;
    bgp[it] = W + (size_t)(n0 + row) * K + seg8;
    al[it] = As + (w * 32 + it * 16) * 32;
    bl[it] = Bs + (w * 32 + it * 16) * 32;
  }

  for (int k0 = 0; k0 < K; k0 += 32) {
#pragma unroll
    for (int it = 0; it < 2; ++it) {
      async16(agp[it] + k0, al[it]);
      async16(bgp[it] + k0, bl[it]);
    }
    __syncthreads();
    bf16x8 af[4], bfv[4];
#pragma unroll
    for (int i = 0; i < 4; ++i)
      af[i] = *(const bf16x8*)(As + (wm * 64 + i * 16 + fr) * 32 + fk);
#pragma unroll
    for (int j = 0; j < 4; ++j)
      bfv[j] = *(const bf16x8*)(Bs + (wn * 64 + j * 16 + fr) * 32 + fk);
#pragma unroll
    for (int i = 0; i < 4; ++i)
#pragma unroll
      for (int j = 0; j < 4; ++j)
        acc[i][j] = __builtin_amdgcn_mfma_f32_16x16x32_bf16(af[i], bfv[j], acc[i][j], 0, 0, 0);
    __syncthreads();
  }

  const int rquad = (lane >> 4) * 4;
  const int cidx = lane & 15;

  unsigned short* cp; int ldcc, ccol0; bool rel = (relu_flag != 0);
  if (C2 && n0 >= nsplit) { cp = C2; ldcc = ldc2; ccol0 = n0 - nsplit; rel = true; }
  else { cp = C; ldcc = ldc; ccol0 = n0; }

  float bv[4];
#pragma unroll
  for (int j = 0; j < 4; ++j) bv[j] = bi[n0 + wn * 64 + j * 16 + cidx];

  // LDS-bounce epilogue: 4 chunks of 32 rows -> coalesced bf16 stores
#pragma unroll
  for (int c = 0; c < 4; ++c) {
    if (wm == (c >> 1)) {
#pragma unroll
      for (int j = 0; j < 4; ++j) {
#pragma unroll
        for (int ii = 0; ii < 2; ++ii) {
          int i = 2 * (c & 1) + ii;
          int lr = ii * 16 + rquad;
#pragma unroll
          for (int r = 0; r < 4; ++r) {
            float v = acc[i][j][r] + bv[j];
            if (rel) v = fmaxf(v, 0.f);
            fscr[lr + r][wn * 64 + j * 16 + cidx] = v;
          }
        }
      }
    }
    __syncthreads();
#pragma unroll
    for (int q = 0; q < 2; ++q) {
      int sg = t + 256 * q;
      int lr = sg >> 4, cs = (sg & 15) * 8;
      int grow = m0 + c * 32 + lr;
      if (grow < m_cnt) {
        union { bf16x8 v; unsigned short u[8]; } pk;
#pragma unroll
        for (int x = 0; x < 8; ++x) pk.u[x] = f2bf(fscr[lr][cs + x]);
        *(bf16x8*)(cp + (size_t)(m_start + grow) * ldcc + ccol0 + cs) = pk.v;
      }
    }
    __syncthreads();
  }
}

// ------- k_vgemm: 64xN256 GEMM + exact final dot, no C store ------------------
// z=0..3: ctrl2 expert z (grouped rows; actions -> out via perm scatter)
// z=4   : sp2 dense (v_p -> out[0:BB])
// Per block: 64 rows, all 256 cols; wave w owns rows w*16..w*16+15.
struct VArgs {
  const unsigned short* A_s; const unsigned short* A_c;
  const unsigned short* W_s; const unsigned short* W_c;
  const float* b_s; const float* b_c;
  const float* w3_s; const float* b3_s;
  const float* w3_c; const float* b3_c;
  const int* perm; const int* seg;
  float* out;
};
__launch_bounds__(256)
__global__ void k_vgemm(VArgs a) {
  __shared__ unsigned short As[64 * 32];
  __shared__ unsigned short Bs[256 * 32];
  const int z = blockIdx.z;
  const unsigned short* A; const unsigned short* W; const float* bi;
  int m_start, m_cnt;
  if (z == 4) { A = a.A_s; W = a.W_s; bi = a.b_s; m_start = 0; m_cnt = BB; }
  else {
    A = a.A_c; W = a.W_c + (size_t)z * 65536; bi = a.b_c + z * 256;
    m_start = a.seg[z]; m_cnt = a.seg[z + 1] - m_start;
  }
  const int m0 = blockIdx.x * 64;
  if (m0 >= m_cnt) return;
  const int t = threadIdx.x, w = t >> 6, lane = t & 63;
  const int fr = lane & 15, fk = (lane >> 4) * 8;

  f32x4 acc[16];
#pragma unroll
  for (int j = 0; j < 16; ++j)
#pragma unroll
    for (int r = 0; r < 4; ++r) acc[j][r] = 0.f;

  int arow = m0 + w * 16 + (lane >> 2);
  if (arow >= m_cnt) arow = m_cnt - 1;
  const unsigned short* ap = A + (size_t)(m_start + arow) * 256 + (lane & 3) * 8;
  unsigned short* al = As + (w * 16) * 32;
  const unsigned short* bp[4]; unsigned short* bl[4];
#pragma unroll
  for (int it = 0; it < 4; ++it) {
    int brow = w * 64 + it * 16 + (lane >> 2);
    bp[it] = W + (size_t)brow * 256 + (lane & 3) * 8;
    bl[it] = Bs + (w * 64 + it * 16) * 32;
  }

  for (int k0 = 0; k0 < 256; k0 += 32) {
    async16(ap + k0, al);
#pragma unroll
    for (int it = 0; it < 4; ++it) async16(bp[it] + k0, bl[it]);
    __syncthreads();
    bf16x8 af = *(const bf16x8*)(As + (w * 16 + fr) * 32 + fk);
#pragma unroll
    for (int j = 0; j < 16; ++j) {
      bf16x8 bfv = *(const bf16x8*)(Bs + (j * 16 + fr) * 32 + fk);
      acc[j] = __builtin_amdgcn_mfma_f32_16x16x32_bf16(af, bfv, acc[j], 0, 0, 0);
    }
    __syncthreads();
  }

  const int rquad = (lane >> 4) * 4;
  float bcol[16];
#pragma unroll
  for (int j = 0; j < 16; ++j) bcol[j] = bi[j * 16 + fr];

  if (z == 4) {
    float aw[16];
#pragma unroll
    for (int j = 0; j < 16; ++j) aw[j] = a.w3_s[j * 16 + fr];
#pragma unroll
    for (int r = 0; r < 4; ++r) {
      float s = 0.f;
#pragma unroll
      for (int j = 0; j < 16; ++j)
        s = fmaf(fmaxf(acc[j][r] + bcol[j], 0.f), aw[j], s);
      s += __shfl_xor(s, 1, 64);
      s += __shfl_xor(s, 2, 64);
      s += __shfl_xor(s, 4, 64);
      s += __shfl_xor(s, 8, 64);
      int row = m0 + w * 16 + rquad + r;
      if (fr == 0 && row < m_cnt) a.out[row] = s + a.b3_s[0];
    }
  } else {
    float aw0[16], aw1[16], aw2[16];
#pragma unroll
    for (int j = 0; j < 16; ++j) {
      const float* wp = a.w3_c + (size_t)z * 768 + (j * 16 + fr) * 3;
      aw0[j] = wp[0]; aw1[j] = wp[1]; aw2[j] = wp[2];
    }
#pragma unroll
    for (int r = 0; r < 4; ++r) {
      float s0 = 0.f, s1 = 0.f, s2 = 0.f;
#pragma unroll
      for (int j = 0; j < 16; ++j) {
        float v = fmaxf(acc[j][r] + bcol[j], 0.f);
        s0 = fmaf(v, aw0[j], s0);
        s1 = fmaf(v, aw1[j], s1);
        s2 = fmaf(v, aw2[j], s2);
      }
#pragma unroll
      for (int m = 1; m <= 8; m <<= 1) {
        s0 += __shfl_xor(s0, m, 64);
        s1 += __shfl_xor(s1, m, 64);
        s2 += __shfl_xor(s2, m, 64);
      }
      int row = m0 + w * 16 + rquad + r;
      if (fr == 0 && row < m_cnt) {
        int orig = a.perm[m_start + row];
        float a0 = s0 + a.b3_c[z * 3 + 0];
        float a1 = s1 + a.b3_c[z * 3 + 1];
        float a2 = s2 + a.b3_c[z * 3 + 2];
        a.out[BB + orig]     = 1.f / (1.f + __expf(-a0));   // throttle
        a.out[2 * BB + orig] = 1.f / (1.f + __expf(-a2));   // brake
        a.out[3 * BB + orig] = tanhf(a1);                   // steering
      }
    }
  }
}

// ---------------- atomic-free command bucketing -------------------------------
__global__ void k_count(const int* __restrict__ cmd, int* __restrict__ wavecnt) {
  int i = blockIdx.x * 256 + threadIdx.x;
  int c = cmd[i];
  int wid = i >> 6;
  int lane = threadIdx.x & 63;
#pragma unroll
  for (int cv = 0; cv < NCMD; ++cv) {
    unsigned long long m = __ballot(c == cv);
    if (lane == 0) wavecnt[cv * 512 + wid] = __popcll(m);
  }
}
__global__ void k_scan(const int* __restrict__ wavecnt, int* __restrict__ wavebase,
                       int* __restrict__ offs /*[5]*/) {
  __shared__ int tot[NCMD];
  __shared__ int soffs[NCMD + 1];
  int t = threadIdx.x, c = t >> 6, lane = t & 63;
  int v[8]; int s = 0;
#pragma unroll
  for (int q = 0; q < 8; ++q) { v[q] = wavecnt[c * 512 + lane * 8 + q]; s += v[q]; }
  int p = s;
#pragma unroll
  for (int m = 1; m < 64; m <<= 1) { int o = __shfl_up(p, m, 64); if (lane >= m) p += o; }
  int excl = p - s;
  if (lane == 63) tot[c] = p;
  __syncthreads();
  if (t == 0) {
    int o = 0;
    for (int e = 0; e < NCMD; ++e) { soffs[e] = o; o += tot[e]; }
    soffs[NCMD] = o;
    for (int e = 0; e <= NCMD; ++e) offs[e] = soffs[e];
  }
  __syncthreads();
  int base = soffs[c] + excl;
#pragma unroll
  for (int q = 0; q < 8; ++q) { wavebase[c * 512 + lane * 8 + q] = base; base += v[q]; }
}
__global__ void k_place(const int* __restrict__ cmd, const int* __restrict__ wavebase,
                        int* __restrict__ perm) {
  int i = blockIdx.x * 256 + threadIdx.x;
  int c = cmd[i];
  int wid = i >> 6, lane = threadIdx.x & 63;
  int rank = 0, base = 0;
#pragma unroll
  for (int cv = 0; cv < NCMD; ++cv) {
    unsigned long long m = __ballot(c == cv);
    if (c == cv) {
      rank = __popcll(m & ((1ull << lane) - 1ull));
      base = wavebase[cv * 512 + wid];
    }
  }
  perm[base + rank] = i;
}

static inline size_t align256(size_t x) { return (x + 255) & ~(size_t)255; }

extern "C" void kernel_launch(void* const* d_in, const int* in_sizes, int n_in,
                              void* d_out, int out_size, void* d_ws, size_t ws_size,
                              hipStream_t stream) {
  const float* feat   = (const float*)d_in[0];
  const float* speed  = (const float*)d_in[1];
  const int*   command= (const int*)d_in[2];
  const float* ms_w1  = (const float*)d_in[3];
  const float* ms_b1  = (const float*)d_in[4];
  const float* ms_w2  = (const float*)d_in[5];
  const float* ms_b2  = (const float*)d_in[6];
  const float* ms_w3  = (const float*)d_in[7];
  const float* ms_b3  = (const float*)d_in[8];
  const float* sp_w1  = (const float*)d_in[9];
  const float* sp_b1  = (const float*)d_in[10];
  const float* sp_w2  = (const float*)d_in[11];
  const float* sp_b2  = (const float*)d_in[12];
  const float* sp_w3  = (const float*)d_in[13];
  const float* sp_b3  = (const float*)d_in[14];
  const float* join_w = (const float*)d_in[15];
  const float* join_b = (const float*)d_in[16];
  const float* ctrl_w1= (const float*)d_in[17];
  const float* ctrl_b1= (const float*)d_in[18];
  const float* ctrl_w2= (const float*)d_in[19];
  const float* ctrl_b2= (const float*)d_in[20];
  const float* ctrl_w3= (const float*)d_in[21];
  const float* ctrl_b3= (const float*)d_in[22];
  float* out = (float*)d_out;

  char* ws = (char*)d_ws;
  size_t off = 0;
  auto alloc = [&](size_t bytes) -> char* { char* p = ws + off; off = align256(off + bytes); return p; };

  unsigned short* ajoin  = (unsigned short*)alloc((size_t)BB * 640 * 2);
  unsigned short* joined = (unsigned short*)alloc((size_t)BB * 512 * 2);
  unsigned short* sph1   = (unsigned short*)alloc((size_t)BB * 256 * 2);
  unsigned short* ch1    = (unsigned short*)alloc((size_t)BB * 256 * 2);
  unsigned short* wtp    = (unsigned short*)alloc(1376256ull * 2);
  int* perm    = (int*)alloc((size_t)BB * 4);
  int* cnt     = (int*)alloc(64);        // offs[5] at cnt+4
  int* wavecnt = (int*)alloc(4 * 512 * 4);
  int* wavebase= (int*)alloc(4 * 512 * 4);
  float* b_js    = (float*)alloc(768 * 4);

  unsigned short* wt_js   = wtp;               // [768][640]
  unsigned short* ms_w2t  = wtp + 491520;      // [128][128]
  unsigned short* ms_w3t  = wtp + 507904;      // [128][128]
  unsigned short* sp_w2t  = wtp + 524288;      // [256][256]
  unsigned short* c_w1t   = wtp + 589824;      // [4][256][512]
  unsigned short* c_w2t   = wtp + 1114112;     // [4][256][256]

  PrepArgs P;
  P.s[0] = { join_w, wt_js, 640, 512, 640 };
  P.s[1] = { sp_w1, wt_js + 512 * 640, 512, 256, 640 };
  P.s[2] = { ms_w2, ms_w2t, 128, 128, 128 };
  P.s[3] = { ms_w3, ms_w3t, 128, 128, 128 };
  P.s[4] = { sp_w2, sp_w2t, 256, 256, 256 };
  for (int e = 0; e < 4; ++e) P.s[5 + e] = { ctrl_w1 + (size_t)e * 512 * 256, c_w1t + (size_t)e * 131072, 512, 256, 512 };
  for (int e = 0; e < 4; ++e) P.s[9 + e] = { ctrl_w2 + (size_t)e * 256 * 256, c_w2t + (size_t)e * 65536, 256, 256, 256 };
  P.start[0] = 0;
  for (int i = 0; i < 13; ++i)
    P.start[i + 1] = P.start[i] + (P.s[i].K >> 5) * (P.s[i].N >> 5);
  P.join_b = join_b; P.sp_b1 = sp_b1; P.b_js = b_js;
  P.feat = feat; P.ajoin = ajoin;
  int prep_blocks = 16384 + P.start[13] + 1;

  (void)hipMemsetAsync(wt_js, 0, 768 * 640 * 2, stream);   // zero-pad sp_w1 K tail
  k_prep<<<prep_blocks, 256, 0, stream>>>(P);
  k_ms<<<256, 256, 0, stream>>>(speed, ms_w1, ms_b1, ms_w2t, ms_b2, ms_w3t, ms_b3, ajoin);

  // bucket by command (atomic-free)
  k_count<<<BB / 256, 256, 0, stream>>>(command, wavecnt);
  k_scan<<<1, 256, 0, stream>>>(wavecnt, wavebase, cnt + 4);
  k_place<<<BB / 256, 256, 0, stream>>>(command, wavebase, perm);

  // combined join + sp1: [joined | relu(sph1)] = ajoin @ wt_js^T + b_js
  k_gemm<<<256 * 6, 256, 0, stream>>>(ajoin, 640, nullptr, nullptr,
      wt_js, 0, b_js, 0, joined, 512, sph1, 256, 512, 0, BB, 640);

  // ctrl1 (grouped, gathered rows)
  k_gemm<<<dim3(256 * 2, 1, 4), 256, 0, stream>>>(joined, 512, perm, cnt + 4,
      c_w1t, 131072, ctrl_b1, 256, ch1, 256, nullptr, 0, 1 << 30, 1, BB, 512);

  // sp2+v_p (z=4) and ctrl2+actions (z=0..3), exact dots, direct final writes
  VArgs V;
  V.A_s = sph1; V.A_c = ch1; V.W_s = sp_w2t; V.W_c = c_w2t;
  V.b_s = sp_b2; V.b_c = ctrl_b2;
  V.w3_s = sp_w3; V.b3_s = sp_b3; V.w3_c = ctrl_w3; V.b3_c = ctrl_b3;
  V.perm = perm; V.seg = cnt + 4; V.out = out;
  k_vgemm<<<dim3(512, 1, 5), 256, 0, stream>>>(V);
}

// Round 8
// 265.672 us; speedup vs baseline: 2.0791x; 1.0081x over previous
//
#include <hip/hip_runtime.h>
#include <hip/hip_bf16.h>
#include <stdint.h>
#include <math.h>

#define BB 32768
#define FEAT 512
#define SPD_H 128
#define CTRL_H 256
#define NCMD 4

typedef __attribute__((ext_vector_type(8))) short bf16x8;
typedef __attribute__((ext_vector_type(4))) float f32x4;

__device__ __forceinline__ unsigned short f2bf(float f) {
  union { float f; uint32_t u; } v; v.f = f;
  uint32_t u = v.u;
  return (unsigned short)((u + 0x7fffu + ((u >> 16) & 1u)) >> 16); // RNE
}

// async global->LDS, 16B per lane; LDS dest = wave-uniform base + lane*16
__device__ __forceinline__ void async16(const unsigned short* g, unsigned short* l) {
  __builtin_amdgcn_global_load_lds(
      (const __attribute__((address_space(1))) unsigned int*)g,
      (__attribute__((address_space(3))) unsigned int*)l, 16, 0, 0);
}

// ------ fused prep: feat convert + weight transposes + zero-pad + b_js + count
struct WSeg { const float* src; unsigned short* dst; int K; int N; int ldd; };
struct PrepArgs {
  WSeg s[13];
  int start[14];
  const float* join_b; const float* sp_b1; float* b_js;
  const float* feat; unsigned short* ajoin;
  unsigned short* wt_js;               // for zero-pad region
  const int* cmd; int* wavecnt;        // bucketing counts
};
__global__ void k_prep(PrepArgs a) {
  int bx = blockIdx.x, t = threadIdx.x;
  if (bx < 16384) {          // feat f32 -> bf16 into ajoin[:,0:512] (stride 640)
    int idx = bx * 256 + t;
    int i = idx >> 7;
    int j4 = (idx & 127) << 2;
    float4 f = *(const float4*)(a.feat + (size_t)i * FEAT + j4);
    ushort4 o;
    o.x = f2bf(f.x); o.y = f2bf(f.y); o.z = f2bf(f.z); o.w = f2bf(f.w);
    *(ushort4*)(a.ajoin + (size_t)i * 640 + j4) = o;
    return;
  }
  int rel = bx - 16384;
  int wt_tiles = a.start[13];
  if (rel < wt_tiles) {      // 32x32 transpose tile
    int si = 0;
    while (rel >= a.start[si + 1]) ++si;
    WSeg sg = a.s[si];
    int tile = rel - a.start[si];
    int tkx = sg.K >> 5;
    int tn = tile / tkx;
    int tk = tile - tn * tkx;
    int k0 = tk * 32, n0 = tn * 32;
    __shared__ float tb[32][33];
    int tx = t & 31, ty = t >> 5;
#pragma unroll
    for (int j = 0; j < 4; ++j)
      tb[ty + j * 8][tx] = sg.src[(size_t)(k0 + ty + j * 8) * sg.N + n0 + tx];
    __syncthreads();
#pragma unroll
    for (int j = 0; j < 4; ++j)
      sg.dst[(size_t)(n0 + ty + j * 8) * sg.ldd + k0 + tx] = f2bf(tb[tx][ty + j * 8]);
    return;
  }
  rel -= wt_tiles;
  if (rel == 0) {            // zero-pad wt_js rows 512..767, cols 512..639
    union { bf16x8 v; unsigned short u[8]; } z;
#pragma unroll
    for (int x = 0; x < 8; ++x) z.u[x] = 0;
#pragma unroll
    for (int q = 0; q < 16; ++q) {
      int s = t + q * 256;            // 0..4095
      int row = 512 + (s >> 4);
      int col = 512 + (s & 15) * 8;
      *(bf16x8*)(a.wt_js + (size_t)row * 640 + col) = z.v;
    }
    return;
  }
  if (rel == 1) {            // b_js = [join_b | sp_b1]
    for (int i = t; i < 768; i += 256)
      a.b_js[i] = (i < 512) ? a.join_b[i] : a.sp_b1[i - 512];
    return;
  }
  // count blocks: per-wave ballot histogram
  int cb = rel - 2;
  int i = cb * 256 + t;
  int c = a.cmd[i];
  int wid = i >> 6;
  int lane = t & 63;
#pragma unroll
  for (int cv = 0; cv < NCMD; ++cv) {
    unsigned long long m = __ballot(c == cv);
    if (lane == 0) a.wavecnt[cv * 512 + wid] = __popcll(m);
  }
}

// --------- fused measured-speed module: speed -> v, into ajoin[:,512:640] -----
__launch_bounds__(256)
__global__ void k_ms(const float* __restrict__ speed,
                     const float* __restrict__ w1, const float* __restrict__ b1,
                     const unsigned short* __restrict__ w2t, const float* __restrict__ b2,
                     const unsigned short* __restrict__ w3t, const float* __restrict__ b3,
                     unsigned short* __restrict__ ajoin) {
  __shared__ unsigned short hw[128][136];
  __shared__ unsigned short Bs[128 * 32];
  const int m0 = blockIdx.x * 128;
  const int t = threadIdx.x;
  const int w = t >> 6, lane = t & 63;
  const int wm = w & 1, wn = w >> 1;
  const int fr = lane & 15, fk = (lane >> 4) * 8;
  const int rquad = (lane >> 4) * 4, cidx = lane & 15;

  {
    int r = t >> 1, half = t & 1;
    float s = speed[m0 + r];
#pragma unroll
    for (int c0 = 0; c0 < 64; c0 += 4) {
      int c = half * 64 + c0;
      float4 wv = *(const float4*)(w1 + c);
      float4 bv = *(const float4*)(b1 + c);
      hw[r][c + 0] = f2bf(fmaxf(fmaf(s, wv.x, bv.x), 0.f));
      hw[r][c + 1] = f2bf(fmaxf(fmaf(s, wv.y, bv.y), 0.f));
      hw[r][c + 2] = f2bf(fmaxf(fmaf(s, wv.z, bv.z), 0.f));
      hw[r][c + 3] = f2bf(fmaxf(fmaf(s, wv.w, bv.w), 0.f));
    }
  }
  __syncthreads();

  for (int layer = 0; layer < 2; ++layer) {
    const unsigned short* Wt = layer ? w3t : w2t;
    const float* bb = layer ? b3 : b2;
    f32x4 acc[4][4];
#pragma unroll
    for (int i = 0; i < 4; ++i)
#pragma unroll
      for (int j = 0; j < 4; ++j)
#pragma unroll
        for (int r = 0; r < 4; ++r) acc[i][j][r] = 0.f;

    for (int k0 = 0; k0 < 128; k0 += 32) {
#pragma unroll
      for (int it = 0; it < 2; ++it) {
        int row = w * 32 + it * 16 + (lane >> 2);
        async16(Wt + (size_t)row * 128 + k0 + (lane & 3) * 8,
                Bs + (w * 32 + it * 16) * 32);
      }
      __syncthreads();
      bf16x8 af[4], bfv[4];
#pragma unroll
      for (int i = 0; i < 4; ++i)
        af[i] = *(const bf16x8*)(&hw[wm * 64 + i * 16 + fr][k0 + fk]);
#pragma unroll
      for (int j = 0; j < 4; ++j)
        bfv[j] = *(const bf16x8*)(Bs + (wn * 64 + j * 16 + fr) * 32 + fk);
#pragma unroll
      for (int i = 0; i < 4; ++i)
#pragma unroll
        for (int j = 0; j < 4; ++j)
          acc[i][j] = __builtin_amdgcn_mfma_f32_16x16x32_bf16(af[i], bfv[j], acc[i][j], 0, 0, 0);
      __syncthreads();
    }
#pragma unroll
    for (int j = 0; j < 4; ++j) {
      int col = wn * 64 + j * 16 + cidx;
      float bv = bb[col];
#pragma unroll
      for (int i = 0; i < 4; ++i) {
        int row = wm * 64 + i * 16 + rquad;
#pragma unroll
        for (int r = 0; r < 4; ++r) {
          float v = acc[i][j][r] + bv;
          if (layer == 0) v = fmaxf(v, 0.f);
          hw[row + r][col] = f2bf(v);
        }
      }
    }
    __syncthreads();
  }
  {
    int r = t >> 1, half = t & 1;
#pragma unroll
    for (int c8 = 0; c8 < 8; ++c8)
      *(bf16x8*)(ajoin + (size_t)(m0 + r) * 640 + 512 + half * 64 + c8 * 8) =
          *(const bf16x8*)(&hw[r][half * 64 + c8 * 8]);
  }
}

// ---------------- 256x128 bf16 MFMA GEMM, bounce epilogue ---------------------
// 1-D grid: m_tile = gid&127 (256 rows), n_tile = gid>>7; z = expert.
// Waves 2x2: wave (wm,wn) owns rows wm*128+i*16 (i<8), cols wn*64+j*16 (j<4).
__launch_bounds__(256, 2)
__global__ void k_gemm(const unsigned short* __restrict__ A, int lda,
                       const int* __restrict__ perm,
                       const int* __restrict__ seg,
                       const unsigned short* __restrict__ Wt, int wstride,
                       const float* __restrict__ bias, int bstride,
                       unsigned short* __restrict__ C, int ldc,
                       unsigned short* __restrict__ C2, int ldc2, int nsplit,
                       int relu_flag, int M, int K) {
  __shared__ unsigned short As[256 * 32];
  __shared__ unsigned short Bs[128 * 32];
  __shared__ float fscr[32][132];

  const int gid = blockIdx.x;
  const int mt = gid & 127;
  const int nt = gid >> 7;
  const int e = blockIdx.z;
  int m_start = 0, m_cnt = M;
  if (seg) { m_start = seg[e]; m_cnt = seg[e + 1] - m_start; }
  const int m0 = mt * 256;
  if (m0 >= m_cnt) return;
  const int n0 = nt * 128;
  const unsigned short* W = Wt + (size_t)e * wstride;
  const float* bi = bias + (size_t)e * bstride;

  const int t = threadIdx.x;
  const int w = t >> 6, lane = t & 63;
  const int wm = w & 1, wn = w >> 1;

  f32x4 acc[8][4];
#pragma unroll
  for (int i = 0; i < 8; ++i)
#pragma unroll
    for (int j = 0; j < 4; ++j)
#pragma unroll
      for (int r = 0; r < 4; ++r) acc[i][j][r] = 0.f;

  const int fr = lane & 15;
  const int fk = (lane >> 4) * 8;

  // staging: A 256x32 (4 insts), B 128x32 (2 insts); 16B/lane each
  const unsigned short* gpA[4]; unsigned short* ldA[4];
  const unsigned short* gpB[2]; unsigned short* ldB[2];
#pragma unroll
  for (int it = 0; it < 4; ++it) {
    int s = t + it * 256;
    int row = s >> 2, sg8 = (s & 3) * 8;
    int rl = m0 + row;
    if (rl >= m_cnt) rl = m_cnt - 1;
    int grow = perm ? perm[m_start + rl] : (m_start + rl);
    gpA[it] = A + (size_t)grow * lda + sg8;
    ldA[it] = As + (w * 16 + it * 64) * 32;
  }
#pragma unroll
  for (int it = 0; it < 2; ++it) {
    int s = t + it * 256;
    int row = s >> 2, sg8 = (s & 3) * 8;
    gpB[it] = W + (size_t)(n0 + row) * K + sg8;
    ldB[it] = Bs + (w * 16 + it * 64) * 32;
  }

  for (int k0 = 0; k0 < K; k0 += 32) {
#pragma unroll
    for (int it = 0; it < 4; ++it) async16(gpA[it] + k0, ldA[it]);
#pragma unroll
    for (int it = 0; it < 2; ++it) async16(gpB[it] + k0, ldB[it]);
    __syncthreads();
    bf16x8 bfv[4];
#pragma unroll
    for (int j = 0; j < 4; ++j)
      bfv[j] = *(const bf16x8*)(Bs + (wn * 64 + j * 16 + fr) * 32 + fk);
#pragma unroll
    for (int i = 0; i < 8; ++i) {
      bf16x8 af = *(const bf16x8*)(As + (wm * 128 + i * 16 + fr) * 32 + fk);
#pragma unroll
      for (int j = 0; j < 4; ++j)
        acc[i][j] = __builtin_amdgcn_mfma_f32_16x16x32_bf16(af, bfv[j], acc[i][j], 0, 0, 0);
    }
    __syncthreads();
  }

  const int rquad = (lane >> 4) * 4;
  const int cidx = lane & 15;

  unsigned short* cp; int ldcc, ccol0; bool rel = (relu_flag != 0);
  if (C2 && n0 >= nsplit) { cp = C2; ldcc = ldc2; ccol0 = n0 - nsplit; rel = true; }
  else { cp = C; ldcc = ldc; ccol0 = n0; }

  float bv[4];
#pragma unroll
  for (int j = 0; j < 4; ++j) bv[j] = bi[n0 + wn * 64 + j * 16 + cidx];

  // LDS-bounce epilogue: 8 chunks of 32 rows -> coalesced bf16 stores
#pragma unroll
  for (int c = 0; c < 8; ++c) {
    if (wm == (c >> 2)) {
#pragma unroll
      for (int j = 0; j < 4; ++j) {
#pragma unroll
        for (int ii = 0; ii < 2; ++ii) {
          int i = (c & 3) * 2 + ii;
          int lr = ii * 16 + rquad;
#pragma unroll
          for (int r = 0; r < 4; ++r) {
            float v = acc[i][j][r] + bv[j];
            if (rel) v = fmaxf(v, 0.f);
            fscr[lr + r][wn * 64 + j * 16 + cidx] = v;
          }
        }
      }
    }
    __syncthreads();
#pragma unroll
    for (int q = 0; q < 2; ++q) {
      int sg = t + 256 * q;
      int lr = sg >> 4, cs = (sg & 15) * 8;
      int grow = m0 + c * 32 + lr;
      if (grow < m_cnt) {
        union { bf16x8 v; unsigned short u[8]; } pk;
#pragma unroll
        for (int x = 0; x < 8; ++x) pk.u[x] = f2bf(fscr[lr][cs + x]);
        *(bf16x8*)(cp + (size_t)(m_start + grow) * ldcc + ccol0 + cs) = pk.v;
      }
    }
    __syncthreads();
  }
}

// ------- k_vgemm: 64xN256 GEMM + exact final dot, no C store ------------------
struct VArgs {
  const unsigned short* A_s; const unsigned short* A_c;
  const unsigned short* W_s; const unsigned short* W_c;
  const float* b_s; const float* b_c;
  const float* w3_s; const float* b3_s;
  const float* w3_c; const float* b3_c;
  const int* perm; const int* seg;
  float* out;
};
__launch_bounds__(256)
__global__ void k_vgemm(VArgs a) {
  __shared__ unsigned short As[64 * 32];
  __shared__ unsigned short Bs[256 * 32];
  const int z = blockIdx.z;
  const unsigned short* A; const unsigned short* W; const float* bi;
  int m_start, m_cnt;
  if (z == 4) { A = a.A_s; W = a.W_s; bi = a.b_s; m_start = 0; m_cnt = BB; }
  else {
    A = a.A_c; W = a.W_c + (size_t)z * 65536; bi = a.b_c + z * 256;
    m_start = a.seg[z]; m_cnt = a.seg[z + 1] - m_start;
  }
  const int m0 = blockIdx.x * 64;
  if (m0 >= m_cnt) return;
  const int t = threadIdx.x, w = t >> 6, lane = t & 63;
  const int fr = lane & 15, fk = (lane >> 4) * 8;

  f32x4 acc[16];
#pragma unroll
  for (int j = 0; j < 16; ++j)
#pragma unroll
    for (int r = 0; r < 4; ++r) acc[j][r] = 0.f;

  int arow = m0 + w * 16 + (lane >> 2);
  if (arow >= m_cnt) arow = m_cnt - 1;
  const unsigned short* ap = A + (size_t)(m_start + arow) * 256 + (lane & 3) * 8;
  unsigned short* al = As + (w * 16) * 32;
  const unsigned short* bp[4]; unsigned short* bl[4];
#pragma unroll
  for (int it = 0; it < 4; ++it) {
    int brow = w * 64 + it * 16 + (lane >> 2);
    bp[it] = W + (size_t)brow * 256 + (lane & 3) * 8;
    bl[it] = Bs + (w * 64 + it * 16) * 32;
  }

  for (int k0 = 0; k0 < 256; k0 += 32) {
    async16(ap + k0, al);
#pragma unroll
    for (int it = 0; it < 4; ++it) async16(bp[it] + k0, bl[it]);
    __syncthreads();
    bf16x8 af = *(const bf16x8*)(As + (w * 16 + fr) * 32 + fk);
#pragma unroll
    for (int j = 0; j < 16; ++j) {
      bf16x8 bfv = *(const bf16x8*)(Bs + (j * 16 + fr) * 32 + fk);
      acc[j] = __builtin_amdgcn_mfma_f32_16x16x32_bf16(af, bfv, acc[j], 0, 0, 0);
    }
    __syncthreads();
  }

  const int rquad = (lane >> 4) * 4;
  float bcol[16];
#pragma unroll
  for (int j = 0; j < 16; ++j) bcol[j] = bi[j * 16 + fr];

  if (z == 4) {
    float aw[16];
#pragma unroll
    for (int j = 0; j < 16; ++j) aw[j] = a.w3_s[j * 16 + fr];
#pragma unroll
    for (int r = 0; r < 4; ++r) {
      float s = 0.f;
#pragma unroll
      for (int j = 0; j < 16; ++j)
        s = fmaf(fmaxf(acc[j][r] + bcol[j], 0.f), aw[j], s);
      s += __shfl_xor(s, 1, 64);
      s += __shfl_xor(s, 2, 64);
      s += __shfl_xor(s, 4, 64);
      s += __shfl_xor(s, 8, 64);
      int row = m0 + w * 16 + rquad + r;
      if (fr == 0 && row < m_cnt) a.out[row] = s + a.b3_s[0];
    }
  } else {
    float aw0[16], aw1[16], aw2[16];
#pragma unroll
    for (int j = 0; j < 16; ++j) {
      const float* wp = a.w3_c + (size_t)z * 768 + (j * 16 + fr) * 3;
      aw0[j] = wp[0]; aw1[j] = wp[1]; aw2[j] = wp[2];
    }
#pragma unroll
    for (int r = 0; r < 4; ++r) {
      float s0 = 0.f, s1 = 0.f, s2 = 0.f;
#pragma unroll
      for (int j = 0; j < 16; ++j) {
        float v = fmaxf(acc[j][r] + bcol[j], 0.f);
        s0 = fmaf(v, aw0[j], s0);
        s1 = fmaf(v, aw1[j], s1);
        s2 = fmaf(v, aw2[j], s2);
      }
#pragma unroll
      for (int m = 1; m <= 8; m <<= 1) {
        s0 += __shfl_xor(s0, m, 64);
        s1 += __shfl_xor(s1, m, 64);
        s2 += __shfl_xor(s2, m, 64);
      }
      int row = m0 + w * 16 + rquad + r;
      if (fr == 0 && row < m_cnt) {
        int orig = a.perm[m_start + row];
        float a0 = s0 + a.b3_c[z * 3 + 0];
        float a1 = s1 + a.b3_c[z * 3 + 1];
        float a2 = s2 + a.b3_c[z * 3 + 2];
        a.out[BB + orig]     = 1.f / (1.f + __expf(-a0));   // throttle
        a.out[2 * BB + orig] = 1.f / (1.f + __expf(-a2));   // brake
        a.out[3 * BB + orig] = tanhf(a1);                   // steering
      }
    }
  }
}

// ---- place with redundant per-block self-scan (no separate scan kernel) ------
__global__ void k_place(const int* __restrict__ cmd, const int* __restrict__ wavecnt,
                        int* __restrict__ perm, int* __restrict__ offs /*[5]*/) {
  __shared__ int pf[NCMD][4];
  __shared__ int tot[NCMD];
  int t = threadIdx.x, b = blockIdx.x, c = t >> 6, lane = t & 63;
  // wave c scans wavecnt[c][0..511]
  int v[8]; int s = 0;
#pragma unroll
  for (int q = 0; q < 8; ++q) { v[q] = wavecnt[c * 512 + lane * 8 + q]; s += v[q]; }
  int p = s;
#pragma unroll
  for (int m = 1; m < 64; m <<= 1) { int o = __shfl_up(p, m, 64); if (lane >= m) p += o; }
  int excl = p - s;
  if (lane == 63) tot[c] = p;
  // this block's 4 global wids are 4b..4b+3, owned by lane (4b)>>3
  if (lane == ((4 * b) >> 3)) {
    int base_off = (4 * b) & 7;        // 0 or 4
    int run = excl;
#pragma unroll
    for (int q = 0; q < 8; ++q) {
      if (q >= base_off && q < base_off + 4) pf[c][q - base_off] = run;
      run += v[q];
    }
  }
  __syncthreads();
  int soffs[NCMD + 1];
  soffs[0] = 0;
#pragma unroll
  for (int e = 0; e < NCMD; ++e) soffs[e + 1] = soffs[e] + tot[e];
  if (b == 0 && t == 0)
    for (int e = 0; e <= NCMD; ++e) offs[e] = soffs[e];
  // ballot place
  int i = b * 256 + t;
  int mc = cmd[i];
  int lwid = t >> 6;
  int rank = 0, base = 0;
#pragma unroll
  for (int cv = 0; cv < NCMD; ++cv) {
    unsigned long long m = __ballot(mc == cv);
    if (mc == cv) {
      rank = __popcll(m & ((1ull << lane) - 1ull));
      base = soffs[cv] + pf[cv][lwid];
    }
  }
  perm[base + rank] = i;
}

static inline size_t align256(size_t x) { return (x + 255) & ~(size_t)255; }

extern "C" void kernel_launch(void* const* d_in, const int* in_sizes, int n_in,
                              void* d_out, int out_size, void* d_ws, size_t ws_size,
                              hipStream_t stream) {
  const float* feat   = (const float*)d_in[0];
  const float* speed  = (const float*)d_in[1];
  const int*   command= (const int*)d_in[2];
  const float* ms_w1  = (const float*)d_in[3];
  const float* ms_b1  = (const float*)d_in[4];
  const float* ms_w2  = (const float*)d_in[5];
  const float* ms_b2  = (const float*)d_in[6];
  const float* ms_w3  = (const float*)d_in[7];
  const float* ms_b3  = (const float*)d_in[8];
  const float* sp_w1  = (const float*)d_in[9];
  const float* sp_b1  = (const float*)d_in[10];
  const float* sp_w2  = (const float*)d_in[11];
  const float* sp_b2  = (const float*)d_in[12];
  const float* sp_w3  = (const float*)d_in[13];
  const float* sp_b3  = (const float*)d_in[14];
  const float* join_w = (const float*)d_in[15];
  const float* join_b = (const float*)d_in[16];
  const float* ctrl_w1= (const float*)d_in[17];
  const float* ctrl_b1= (const float*)d_in[18];
  const float* ctrl_w2= (const float*)d_in[19];
  const float* ctrl_b2= (const float*)d_in[20];
  const float* ctrl_w3= (const float*)d_in[21];
  const float* ctrl_b3= (const float*)d_in[22];
  float* out = (float*)d_out;

  char* ws = (char*)d_ws;
  size_t off = 0;
  auto alloc = [&](size_t bytes) -> char* { char* p = ws + off; off = align256(off + bytes); return p; };

  unsigned short* ajoin  = (unsigned short*)alloc((size_t)BB * 640 * 2);
  unsigned short* joined = (unsigned short*)alloc((size_t)BB * 512 * 2);
  unsigned short* sph1   = (unsigned short*)alloc((size_t)BB * 256 * 2);
  unsigned short* ch1    = (unsigned short*)alloc((size_t)BB * 256 * 2);
  unsigned short* wtp    = (unsigned short*)alloc(1376256ull * 2);
  int* perm    = (int*)alloc((size_t)BB * 4);
  int* cnt     = (int*)alloc(64);        // offs[5] at cnt+4
  int* wavecnt = (int*)alloc(4 * 512 * 4);
  float* b_js    = (float*)alloc(768 * 4);

  unsigned short* wt_js   = wtp;               // [768][640]
  unsigned short* ms_w2t  = wtp + 491520;      // [128][128]
  unsigned short* ms_w3t  = wtp + 507904;      // [128][128]
  unsigned short* sp_w2t  = wtp + 524288;      // [256][256]
  unsigned short* c_w1t   = wtp + 589824;      // [4][256][512]
  unsigned short* c_w2t   = wtp + 1114112;     // [4][256][256]

  PrepArgs P;
  P.s[0] = { join_w, wt_js, 640, 512, 640 };
  P.s[1] = { sp_w1, wt_js + 512 * 640, 512, 256, 640 };
  P.s[2] = { ms_w2, ms_w2t, 128, 128, 128 };
  P.s[3] = { ms_w3, ms_w3t, 128, 128, 128 };
  P.s[4] = { sp_w2, sp_w2t, 256, 256, 256 };
  for (int e = 0; e < 4; ++e) P.s[5 + e] = { ctrl_w1 + (size_t)e * 512 * 256, c_w1t + (size_t)e * 131072, 512, 256, 512 };
  for (int e = 0; e < 4; ++e) P.s[9 + e] = { ctrl_w2 + (size_t)e * 256 * 256, c_w2t + (size_t)e * 65536, 256, 256, 256 };
  P.start[0] = 0;
  for (int i = 0; i < 13; ++i)
    P.start[i + 1] = P.start[i] + (P.s[i].K >> 5) * (P.s[i].N >> 5);
  P.join_b = join_b; P.sp_b1 = sp_b1; P.b_js = b_js;
  P.feat = feat; P.ajoin = ajoin;
  P.wt_js = wt_js;
  P.cmd = command; P.wavecnt = wavecnt;
  int prep_blocks = 16384 + P.start[13] + 2 + 128;

  k_prep<<<prep_blocks, 256, 0, stream>>>(P);
  k_ms<<<256, 256, 0, stream>>>(speed, ms_w1, ms_b1, ms_w2t, ms_b2, ms_w3t, ms_b3, ajoin);
  k_place<<<BB / 256, 256, 0, stream>>>(command, wavecnt, perm, cnt + 4);

  // combined join + sp1: [joined | relu(sph1)] = ajoin @ wt_js^T + b_js
  k_gemm<<<128 * 6, 256, 0, stream>>>(ajoin, 640, nullptr, nullptr,
      wt_js, 0, b_js, 0, joined, 512, sph1, 256, 512, 0, BB, 640);

  // ctrl1 (grouped, gathered rows)
  k_gemm<<<dim3(128 * 2, 1, 4), 256, 0, stream>>>(joined, 512, perm, cnt + 4,
      c_w1t, 131072, ctrl_b1, 256, ch1, 256, nullptr, 0, 1 << 30, 1, BB, 512);

  // sp2+v_p (z=4) and ctrl2+actions (z=0..3)
  VArgs V;
  V.A_s = sph1; V.A_c = ch1; V.W_s = sp_w2t; V.W_c = c_w2t;
  V.b_s = sp_b2; V.b_c = ctrl_b2;
  V.w3_s = sp_w3; V.b3_s = sp_b3; V.w3_c = ctrl_w3; V.b3_c = ctrl_b3;
  V.perm = perm; V.seg = cnt + 4; V.out = out;
  k_vgemm<<<dim3(512, 1, 5), 256, 0, stream>>>(V);
}